// Round 7
// baseline (724.514 us; speedup 1.0000x reference)
//
#include <hip/hip_runtime.h>
#include <hip/hip_bf16.h>

// ---------------------------------------------------------------------------
// TransformerDecoderLayer on MI355X. bf16 MFMA, f32 accumulate.
// R7: dispatch consolidation. prep = transpose+cvt+permute+LN1 in one kernel;
// Nh/Mh build on the 128-tile kernel at full grid; self-rownorm fused into PV
// (in-register row sums + W write). 12 dispatches (was 16).
// ---------------------------------------------------------------------------

typedef __attribute__((ext_vector_type(4))) float f32x4;
typedef __attribute__((ext_vector_type(8))) short bf16x8;

#define SCALE 0.04419417382415922f   // 1/sqrt(512)

__device__ __forceinline__ short f2bf(float f) {
  __hip_bfloat16 h = __float2bfloat16(f);
  short s; __builtin_memcpy(&s, &h, 2); return s;
}
__device__ __forceinline__ float bf2f(short s) {
  unsigned int u = ((unsigned int)(unsigned short)s) << 16;
  float f; __builtin_memcpy(&f, &u, 4); return f;
}

__device__ __forceinline__ void gload16(const void* g, void* lds) {
  __builtin_amdgcn_global_load_lds(
      (const __attribute__((address_space(1))) unsigned int*)g,
      (__attribute__((address_space(3))) unsigned int*)lds, 16, 0, 0);
}

// ---------------- block reductions ----------------
__device__ __forceinline__ float block_sum(float v, float* sm) {
  #pragma unroll
  for (int o = 1; o < 64; o <<= 1) v += __shfl_xor(v, o, 64);
  int w = threadIdx.x >> 6;
  if ((threadIdx.x & 63) == 0) sm[w] = v;
  __syncthreads();
  float r = sm[0] + sm[1] + sm[2] + sm[3];
  __syncthreads();
  return r;
}

// ---------------- prep: LN1+tokb | cvt wv/w1/w2 | permute_wo | transpose ----
// blocks [0,4096): LN1 row; [4096,8192): cvt; [8192,16384): permute_wo;
// [16384,24576): 32x32 transposes of wq/wk/cwq/cwk -> QT/KT (bf16).
__global__ __launch_bounds__(256) void prep(
    const float* __restrict__ tokens, const float* __restrict__ ln1g,
    const float* __restrict__ ln1b,
    const float* __restrict__ wv, const float* __restrict__ w1,
    const float* __restrict__ w2, const float* __restrict__ wo,
    const float* __restrict__ wq, const float* __restrict__ wk,
    const float* __restrict__ cwq, const float* __restrict__ cwk,
    short* __restrict__ xb, short* __restrict__ tokb,
    short* __restrict__ wvb, short* __restrict__ w1b, short* __restrict__ w2b,
    short* __restrict__ wop, short* __restrict__ QT, short* __restrict__ KT) {
  __shared__ float sm[4];
  __shared__ float tile[32][33];
  const int bid = blockIdx.x;
  if (bid < 4096) {
    size_t row = bid;
    const float2 v = reinterpret_cast<const float2*>(tokens + row * 512)[threadIdx.x];
    short2 ro; ro.x = f2bf(v.x); ro.y = f2bf(v.y);
    reinterpret_cast<short2*>(tokb + row * 512)[threadIdx.x] = ro;
    float mu = block_sum(v.x + v.y, sm) * (1.0f / 512.0f);
    float dx = v.x - mu, dy = v.y - mu;
    float var = block_sum(dx * dx + dy * dy, sm) * (1.0f / 512.0f);
    float rs = rsqrtf(var + 1e-6f);
    int c = threadIdx.x * 2;
    short2 o;
    o.x = f2bf(dx * rs * ln1g[c] + ln1b[c]);
    o.y = f2bf(dy * rs * ln1g[c + 1] + ln1b[c + 1]);
    reinterpret_cast<short2*>(xb + row * 512)[threadIdx.x] = o;
  } else if (bid < 8192) {
    int i = (bid - 4096) * 256 + threadIdx.x;   // 1,048,576 float4 jobs
    const float* src; short* dst; int k;
    if (i < 524288)      { src = wv; dst = wvb; k = i; }
    else if (i < 786432) { src = w1; dst = w1b; k = i - 524288; }
    else                 { src = w2; dst = w2b; k = i - 786432; }
    float4 v = reinterpret_cast<const float4*>(src)[k];
    short4 o; o.x = f2bf(v.x); o.y = f2bf(v.y); o.z = f2bf(v.z); o.w = f2bf(v.w);
    reinterpret_cast<short4*>(dst)[k] = o;
  } else if (bid < 16384) {
    int i = (bid - 8192) * 256 + threadIdx.x;   // wo permute, 2,097,152 elems
    int o = i >> 12, j = i & 4095;
    int h = j >> 9, d = j & 511;
    int h2 = d >> 6, e = d & 63;
    wop[i] = f2bf(wo[(o << 12) + h2 * 512 + h * 64 + e]);
  } else {
    const int idx = bid - 16384;                // 8192: 32 tensor-heads x 256 tiles
    const int z = idx >> 8, t = z >> 3, h = z & 7;
    const int tl = idx & 255, by = tl >> 4, bx = tl & 15;
    const float* in = (t == 0) ? wq : (t == 1) ? wk : (t == 2) ? cwq : cwk;
    short* out = (t == 0) ? QT : (t == 1) ? KT
               : (t == 2) ? (QT + 8ull * 262144) : (KT + 8ull * 262144);
    const int tx = threadIdx.x & 31, ty = threadIdx.x >> 5;
    const size_t base = (size_t)h * 262144;
    #pragma unroll
    for (int r = 0; r < 4; ++r) {
      const int o = by * 32 + ty + r * 8;
      tile[ty + r * 8][tx] = in[base + (size_t)o * 512 + bx * 32 + tx];
    }
    __syncthreads();
    #pragma unroll
    for (int r = 0; r < 4; ++r) {
      const int d = bx * 32 + ty + r * 8;
      out[base + (size_t)d * 512 + by * 32 + tx] = f2bf(tile[tx][ty + r * 8]);
    }
  }
}

// ---------------- layernorm (LN2 only) ----------------
__global__ __launch_bounds__(256) void ln_rows(const float* __restrict__ in,
    const float* __restrict__ gw, const float* __restrict__ bw,
    short* __restrict__ out) {
  __shared__ float sm[4];
  size_t row = blockIdx.x;
  const float2 v = reinterpret_cast<const float2*>(in + row * 512)[threadIdx.x];
  float mu = block_sum(v.x + v.y, sm) * (1.0f / 512.0f);
  float dx = v.x - mu, dy = v.y - mu;
  float var = block_sum(dx * dx + dy * dy, sm) * (1.0f / 512.0f);
  float rs = rsqrtf(var + 1e-6f);
  int c = threadIdx.x * 2;
  short2 o;
  o.x = f2bf(dx * rs * gw[c] + bw[c]);
  o.y = f2bf(dy * rs * gw[c + 1] + bw[c + 1]);
  reinterpret_cast<short2*>(out + row * 512)[threadIdx.x] = o;
}

// ---------------- rownorm (cross only): W = E / rowsum(E) ------------------
__global__ __launch_bounds__(256) void rownorm(const short* __restrict__ E,
                                               float* __restrict__ W) {
  const int wv = threadIdx.x >> 6, l = threadIdx.x & 63;
  const size_t row = (size_t)blockIdx.x * 4 + wv;
  const short* ep = E + row * 1024;
  float s = 0.f;
  #pragma unroll
  for (int c = 0; c < 2; ++c) {
    bf16x8 v = *reinterpret_cast<const bf16x8*>(ep + c * 512 + l * 8);
    #pragma unroll
    for (int j = 0; j < 8; ++j) s += bf2f(v[j]);
  }
  #pragma unroll
  for (int o = 1; o < 64; o <<= 1) s += __shfl_xor(s, o, 64);
  const float inv = 1.0f / s;
  float* wp = W + row * 1024;
  #pragma unroll
  for (int c = 0; c < 4; ++c) {
    const int c0 = c * 256 + l * 4;
    short4 v = *reinterpret_cast<const short4*>(ep + c0);
    float4 o4;
    o4.x = bf2f(v.x) * inv; o4.y = bf2f(v.y) * inv;
    o4.z = bf2f(v.z) * inv; o4.w = bf2f(v.w) * inv;
    *reinterpret_cast<float4*>(wp + c0) = o4;
  }
}

// ===========================================================================
// 8-phase pipelined 256x256 GEMM.
// EPI 0: x*[NhT;wv] -> qn [B,H,L,D], v^T [B,H,D,L]
// EPI 1: self E=exp(qn.x^T*SCALE-8) bf16, triangular; B per-batch stride
// EPI 2: PV; in-register row sums -> inv; ctx*inv -> comb; W=E*inv -> fout
// EPI 6: tM = t*MhT
// EPI 7: cross E bf16; B per-batch stride
// ===========================================================================
#define STAGEH(ldsoff, gbase, grow0, kcol0) do {                               \
    const int rr_ = tid >> 3;                                                  \
    const int cc_ = ((tid & 7) ^ (rr_ & 7)) << 3;                              \
    gload16((gbase) + (size_t)((grow0) + rr_) * K + (kcol0) + cc_,             \
            &sh[(ldsoff) + (tid >> 6) * 512]);                                 \
    gload16((gbase) + (size_t)((grow0) + 64 + rr_) * K + (kcol0) + cc_,        \
            &sh[(ldsoff) + 4096 + (tid >> 6) * 512]);                          \
  } while (0)

#define READ_A(g) do {                                                         \
    _Pragma("unroll")                                                          \
    for (int mi = 0; mi < 4; ++mi) {                                           \
      const int row_ = wm * 64 + mi * 16 + lr;                                 \
      _Pragma("unroll")                                                        \
      for (int ks = 0; ks < 2; ++ks)                                           \
        a[mi][ks] = *reinterpret_cast<const bf16x8*>(                          \
            &sh[abase + (g) * 8192 + row_ * 64 + ((((ks << 2) + kh) ^ sx) << 3)]); \
    } } while (0)

#define READ_B(dst, n) do {                                                    \
    _Pragma("unroll")                                                          \
    for (int njj = 0; njj < 2; ++njj) {                                        \
      const int row_ = wn * 32 + njj * 16 + lr;                                \
      _Pragma("unroll")                                                        \
      for (int ks = 0; ks < 2; ++ks)                                           \
        dst[njj][ks] = *reinterpret_cast<const bf16x8*>(                       \
            &sh[bbase + (n) * 8192 + row_ * 64 + ((((ks << 2) + kh) ^ sx) << 3)]); \
    } } while (0)

#define MFMA_PH(g, n, bb) do {                                                 \
    __builtin_amdgcn_s_setprio(1);                                             \
    _Pragma("unroll")                                                          \
    for (int mi = 0; mi < 4; ++mi)                                             \
      _Pragma("unroll")                                                        \
      for (int njj = 0; njj < 2; ++njj)                                        \
        _Pragma("unroll")                                                      \
        for (int ks = 0; ks < 2; ++ks)                                         \
          acc[(g) * 4 + mi][(n) * 2 + njj] =                                   \
              __builtin_amdgcn_mfma_f32_16x16x32_bf16(                         \
                  bb[njj][ks], a[mi][ks], acc[(g) * 4 + mi][(n) * 2 + njj],    \
                  0, 0, 0);                                                    \
    __builtin_amdgcn_s_setprio(0); } while (0)

template<int EPI>
__global__ __launch_bounds__(512, 1) void gemm256(
    const short* __restrict__ A, const short* __restrict__ Bw,
    int K, long long sA, long long sB,
    float* __restrict__ fout, short* __restrict__ bout,
    short* __restrict__ bout3,
    const short* __restrict__ A2, const short* __restrict__ B2) {
  __shared__ short sh[65536];               // 128 KiB
  const int tid = threadIdx.x;
  const int w = tid >> 6, l = tid & 63;
  const int wm = w >> 2, wn = w & 3;        // 2 M-waves x 4 N-waves
  const int lr = l & 15, kh = l >> 4;
  const int sx = lr & 7;
  int bx = blockIdx.x, by = blockIdx.y;
  const int z = blockIdx.z;
  if constexpr (EPI == 1) {                 // triangular: bx<=by
    int idx = blockIdx.x;
    by = 0;
    while ((by + 1) * (by + 2) / 2 <= idx) ++by;
    bx = idx - by * (by + 1) / 2;
  }
  const int bm = by * 256, bn = bx * 256;
  const short* Ab; const short* Bb;
  if constexpr (EPI == 1 || EPI == 7) {
    Ab = A + (size_t)z * sA;                 // per-(b,h)
    Bb = Bw + (size_t)(z >> 3) * sB;         // per-batch (shared across heads)
  } else if constexpr (EPI == 6) {
    Ab = z ? A2 : A; Bb = z ? B2 : Bw;
  } else {
    Ab = A + (size_t)z * sA; Bb = Bw + (size_t)z * sB;
  }

  const int kend = (EPI == 2) ? (bm + 256) : K;
  const int NT = kend >> 6;

  f32x4 acc[8][4];
  #pragma unroll
  for (int mf = 0; mf < 8; ++mf)
    #pragma unroll
    for (int nf = 0; nf < 4; ++nf) acc[mf][nf] = (f32x4){0.f, 0.f, 0.f, 0.f};
  float rs[8] = {0.f, 0.f, 0.f, 0.f, 0.f, 0.f, 0.f, 0.f};

  // prologue: tile0 all 4 halves, then tile1 {A0, B0, A1}
  STAGEH(0,     Ab, bm,       0);
  STAGEH(8192,  Ab, bm + 128, 0);
  STAGEH(32768, Bb, bn,       0);
  STAGEH(40960, Bb, bn + 128, 0);
  if (NT > 1) {
    STAGEH(16384, Ab, bm,       64);
    STAGEH(49152, Bb, bn,       64);
    STAGEH(24576, Ab, bm + 128, 64);
    asm volatile("s_waitcnt vmcnt(6)" ::: "memory");
  } else {
    asm volatile("s_waitcnt vmcnt(0)" ::: "memory");
  }
  __builtin_amdgcn_s_barrier();

  bf16x8 a[4][2], b0[2][2], b1[2][2];

  for (int t = 0; t < NT; ++t) {
    const int cb = t & 1;
    const int abase = cb * 16384;
    const int bbase = 32768 + cb * 16384;
    const int b2base = 32768 + (cb ^ 1) * 16384;
    const int kc1 = (t + 1) << 6, kc2 = (t + 2) << 6;
    const bool m1 = (t + 1 < NT), m2 = (t + 2 < NT);

    // ---- ph0 ----
    READ_A(0);
    READ_B(b0, 0);
    if (m1) STAGEH(b2base + 8192, Bb, bn + 128, kc1);
    __builtin_amdgcn_s_barrier();
    asm volatile("s_waitcnt lgkmcnt(0)" ::: "memory");
    __builtin_amdgcn_sched_barrier(0);
    MFMA_PH(0, 0, b0);
    if constexpr (EPI == 2) {               // row-sum of A-g0 (values valid)
      #pragma unroll
      for (int mi = 0; mi < 4; ++mi)
        #pragma unroll
        for (int ks = 0; ks < 2; ++ks)
          #pragma unroll
          for (int jj = 0; jj < 8; ++jj) rs[mi] += bf2f(a[mi][ks][jj]);
    }
    __builtin_amdgcn_s_barrier();

    // ---- ph1 ----
    READ_B(b1, 1);
    if (m2) STAGEH(abase, Ab, bm, kc2);
    __builtin_amdgcn_s_barrier();
    asm volatile("s_waitcnt lgkmcnt(0)" ::: "memory");
    __builtin_amdgcn_sched_barrier(0);
    MFMA_PH(0, 1, b1);
    __builtin_amdgcn_s_barrier();

    // ---- ph2 ----
    READ_A(1);
    if (m2) STAGEH(bbase, Bb, bn, kc2);
    __builtin_amdgcn_s_barrier();
    asm volatile("s_waitcnt lgkmcnt(0)" ::: "memory");
    __builtin_amdgcn_sched_barrier(0);
    MFMA_PH(1, 0, b0);
    if constexpr (EPI == 2) {               // row-sum of A-g1
      #pragma unroll
      for (int mi = 0; mi < 4; ++mi)
        #pragma unroll
        for (int ks = 0; ks < 2; ++ks)
          #pragma unroll
          for (int jj = 0; jj < 8; ++jj) rs[4 + mi] += bf2f(a[mi][ks][jj]);
    }
    __builtin_amdgcn_s_barrier();

    // ---- ph3 ----
    if (m2) STAGEH(abase + 8192, Ab, bm + 128, kc2);
    __builtin_amdgcn_s_barrier();
    __builtin_amdgcn_sched_barrier(0);
    MFMA_PH(1, 1, b1);
    if (m1) {
      if (m2) asm volatile("s_waitcnt vmcnt(6)" ::: "memory");
      else    asm volatile("s_waitcnt vmcnt(0)" ::: "memory");
      __builtin_amdgcn_s_barrier();
    }
  }

  float* inv_sm = reinterpret_cast<float*>(sh);
  if constexpr (EPI == 2) {
    // reduce across kh lanes (16,32); every lane ends with its rows' inv
    #pragma unroll
    for (int mf = 0; mf < 8; ++mf) {
      rs[mf] += __shfl_xor(rs[mf], 16, 64);
      rs[mf] += __shfl_xor(rs[mf], 32, 64);
      rs[mf] = 1.0f / rs[mf];
    }
    if (wn == 0 && kh == 0) {               // one writer set per row
      #pragma unroll
      for (int mf = 0; mf < 8; ++mf)
        inv_sm[(mf >> 2) * 128 + wm * 64 + (mf & 3) * 16 + lr] = rs[mf];
    }
  }

  // Epilogue. Swapped-operand C layout: lane owns row (lr field) x 4 cols.
  #pragma unroll
  for (int mf = 0; mf < 8; ++mf) {
    const int grow = bm + (mf >> 2) * 128 + wm * 64 + (mf & 3) * 16 + lr;
    #pragma unroll
    for (int nf = 0; nf < 4; ++nf) {
      const int gcol0 = bn + (nf >> 1) * 128 + wn * 32 + (nf & 1) * 16 + kh * 4;
      const float v0 = acc[mf][nf][0], v1 = acc[mf][nf][1];
      const float v2 = acc[mf][nf][2], v3 = acc[mf][nf][3];
      if constexpr (EPI == 0) {
        const int b = grow >> 10, lw = grow & 1023;
        if (bn < 4096) {    // qn [B,H,L,D]
          const int h = gcol0 >> 9, o = gcol0 & 511;
          *reinterpret_cast<short4*>(&bout[(((size_t)(b * 8 + h)) * 1024 + lw) * 512 + o]) =
              make_short4(f2bf(v0), f2bf(v1), f2bf(v2), f2bf(v3));
        } else {            // v^T [B,H,D,L]
          const int n2 = gcol0 - 4096, h = n2 >> 9, o = n2 & 511;
          const size_t base = ((size_t)(b * 8 + h)) * 512;
          bout3[(base + o + 0) * 1024 + lw] = f2bf(v0);
          bout3[(base + o + 1) * 1024 + lw] = f2bf(v1);
          bout3[(base + o + 2) * 1024 + lw] = f2bf(v2);
          bout3[(base + o + 3) * 1024 + lw] = f2bf(v3);
        }
      } else if constexpr (EPI == 1) {
        short4 o;
        o.x = (gcol0 + 0 > grow) ? (short)0 : f2bf(__expf(v0 * SCALE - 8.0f));
        o.y = (gcol0 + 1 > grow) ? (short)0 : f2bf(__expf(v1 * SCALE - 8.0f));
        o.z = (gcol0 + 2 > grow) ? (short)0 : f2bf(__expf(v2 * SCALE - 8.0f));
        o.w = (gcol0 + 3 > grow) ? (short)0 : f2bf(__expf(v3 * SCALE - 8.0f));
        *reinterpret_cast<short4*>(&bout[(size_t)z * 1048576 + (size_t)grow * 1024 + gcol0]) = o;
      } else if constexpr (EPI == 2) {
        const float inv = rs[mf];
        const int b = z >> 3, h = z & 7;
        *reinterpret_cast<short4*>(&bout[((size_t)(b * 1024 + grow)) * 4096 + h * 512 + gcol0]) =
            make_short4(f2bf(v0 * inv), f2bf(v1 * inv), f2bf(v2 * inv), f2bf(v3 * inv));
      } else if constexpr (EPI == 6) {
        const int b = grow >> 10, lw = grow & 1023;
        const int h = gcol0 >> 9, o = gcol0 & 511;
        *reinterpret_cast<short4*>(&bout[(((size_t)(b * 8 + h)) * 1024 + lw) * 512 + o]) =
            make_short4(f2bf(v0), f2bf(v1), f2bf(v2), f2bf(v3));
      } else if constexpr (EPI == 7) {
        short4 o;
        o.x = f2bf(__expf(v0 * SCALE - 8.0f));
        o.y = f2bf(__expf(v1 * SCALE - 8.0f));
        o.z = f2bf(__expf(v2 * SCALE - 8.0f));
        o.w = f2bf(__expf(v3 * SCALE - 8.0f));
        *reinterpret_cast<short4*>(&bout[(size_t)z * 1048576 + (size_t)grow * 1024 + gcol0]) = o;
      }
    }
  }

  if constexpr (EPI == 2) {
    // W = E * inv  for rows [bm,bm+256), cols [bx*512 + ch*256, +256)
    __syncthreads();
    const int r = tid >> 1, ch = tid & 1;
    const int colbase = bx * 512 + ch * 256;
    const float inv = inv_sm[r];
    float* wrow = fout + (size_t)z * 1048576 + (size_t)(bm + r) * 1024 + colbase;
    if (colbase < kend) {
      const short* erow = Ab + (size_t)(bm + r) * 1024 + colbase;
      #pragma unroll 8
      for (int j = 0; j < 64; ++j) {
        short4 e = *reinterpret_cast<const short4*>(erow + j * 4);
        float4 o4;
        o4.x = bf2f(e.x) * inv; o4.y = bf2f(e.y) * inv;
        o4.z = bf2f(e.z) * inv; o4.w = bf2f(e.w) * inv;
        *reinterpret_cast<float4*>(wrow + j * 4) = o4;
      }
    } else {
      float4 zz; zz.x = zz.y = zz.z = zz.w = 0.f;
      #pragma unroll 8
      for (int j = 0; j < 64; ++j)
        *reinterpret_cast<float4*>(wrow + j * 4) = zz;
    }
  }
}

// ---------------- 128-tile kernel ----------------
// EPI 3: sa -> fout = fin + val   EPI 4: ffn1-gelu   EPI 5: ffn2
// EPI 8: NhT/MhT build: A=KT+z*256K, B=QT+z*256K; out rows j, cols i
template<int EPI, int BN>
__global__ __launch_bounds__(256, 2) void gemm_nt(
    const short* __restrict__ A, const short* __restrict__ Bw,
    int K, const float* __restrict__ fin, const float* __restrict__ fin2,
    float* __restrict__ fout, short* __restrict__ bout,
    short* __restrict__ bout2) {
  constexpr int NJ = BN / 32;
  __shared__ short As[128 * 32];
  __shared__ short Bs[BN * 32];
  const int tid = threadIdx.x;
  const int w = tid >> 6, l = tid & 63;
  const int wr = w >> 1, wc = w & 1;
  const int lr = l & 15, kh = l >> 4;
  const int bm = blockIdx.y * 128, bn = blockIdx.x * BN;
  const int ar = w * 16 + (l >> 2);
  const int ac = (l & 3) * 8;
  const short* Ab = A; const short* Bb = Bw;
  if constexpr (EPI == 8) {
    Ab = A + (size_t)blockIdx.z * 262144;
    Bb = Bw + (size_t)blockIdx.z * 262144;
  }

  f32x4 acc[4][NJ];
  #pragma unroll
  for (int i = 0; i < 4; ++i)
    #pragma unroll
    for (int j = 0; j < NJ; ++j) acc[i][j] = (f32x4){0.f, 0.f, 0.f, 0.f};

  for (int k0 = 0; k0 < K; k0 += 32) {
    #pragma unroll
    for (int c = 0; c < 2; ++c)
      gload16(Ab + (size_t)(bm + c * 64 + ar) * K + k0 + ac, &As[c * 2048 + w * 512]);
    #pragma unroll
    for (int c = 0; c < BN / 64; ++c)
      gload16(Bb + (size_t)(bn + c * 64 + ar) * K + k0 + ac, &Bs[c * 2048 + w * 512]);
    __syncthreads();
    bf16x8 af[4], bfr[NJ];
    #pragma unroll
    for (int i = 0; i < 4; ++i)
      af[i] = *reinterpret_cast<const bf16x8*>(&As[(wr * 64 + i * 16 + lr) * 32 + kh * 8]);
    #pragma unroll
    for (int j = 0; j < NJ; ++j)
      bfr[j] = *reinterpret_cast<const bf16x8*>(&Bs[(wc * (BN / 2) + j * 16 + lr) * 32 + kh * 8]);
    #pragma unroll
    for (int i = 0; i < 4; ++i)
      #pragma unroll
      for (int j = 0; j < NJ; ++j)
        acc[i][j] = __builtin_amdgcn_mfma_f32_16x16x32_bf16(bfr[j], af[i], acc[i][j], 0, 0, 0);
    __syncthreads();
  }

  #pragma unroll
  for (int i = 0; i < 4; ++i) {
    const int grow = bm + wr * 64 + i * 16 + lr;
    #pragma unroll
    for (int j = 0; j < NJ; ++j) {
      const int gcol0 = bn + wc * (BN / 2) + j * 16 + kh * 4;
      const float v0 = acc[i][j][0], v1 = acc[i][j][1];
      const float v2 = acc[i][j][2], v3 = acc[i][j][3];
      if constexpr (EPI == 3) {
        const size_t idx = (size_t)grow * 512 + gcol0;
        const float4 t4 = *reinterpret_cast<const float4*>(&fin[idx]);
        float4 f; f.x = t4.x + v0; f.y = t4.y + v1; f.z = t4.z + v2; f.w = t4.w + v3;
        *reinterpret_cast<float4*>(&fout[idx]) = f;
      } else if constexpr (EPI == 4) {
        const float4 b4 = *reinterpret_cast<const float4*>(&fin[gcol0]);
        const float x0 = v0 + b4.x, x1 = v1 + b4.y, x2 = v2 + b4.z, x3 = v3 + b4.w;
        const float g0 = 0.5f * x0 * (1.0f + erff(x0 * 0.70710678118654752f));
        const float g1 = 0.5f * x1 * (1.0f + erff(x1 * 0.70710678118654752f));
        const float g2 = 0.5f * x2 * (1.0f + erff(x2 * 0.70710678118654752f));
        const float g3 = 0.5f * x3 * (1.0f + erff(x3 * 0.70710678118654752f));
        *reinterpret_cast<short4*>(&bout[(size_t)grow * 2048 + gcol0]) =
            make_short4(f2bf(g0), f2bf(g1), f2bf(g2), f2bf(g3));
      } else if constexpr (EPI == 5) {
        const size_t idx = (size_t)grow * 512 + gcol0;
        const float4 a4 = *reinterpret_cast<const float4*>(&fin2[idx]);
        const float4 b4 = *reinterpret_cast<const float4*>(&fin[gcol0]);
        float4 f;
        f.x = a4.x + v0 + b4.x; f.y = a4.y + v1 + b4.y;
        f.z = a4.z + v2 + b4.z; f.w = a4.w + v3 + b4.w;
        *reinterpret_cast<float4*>(&fout[idx]) = f;
        *reinterpret_cast<short4*>(&bout[idx]) =
            make_short4(f2bf(f.x), f2bf(f.y), f2bf(f.z), f2bf(f.w));
      } else if constexpr (EPI == 8) {
        short* outp = ((blockIdx.z < 8) ? bout : bout2) +
                      (size_t)(blockIdx.z & 7) * 262144;
        *reinterpret_cast<short4*>(&outp[(size_t)grow * 512 + gcol0]) =
            make_short4(f2bf(v0), f2bf(v1), f2bf(v2), f2bf(v3));
      }
    }
  }
}

// ---------------------------------------------------------------------------
extern "C" void kernel_launch(void* const* d_in, const int* in_sizes, int n_in,
                              void* d_out, int out_size, void* d_ws, size_t ws_size,
                              hipStream_t stream) {
  const float* tokens = (const float*)d_in[0];
  const float* ln1g = (const float*)d_in[3];
  const float* ln1b = (const float*)d_in[4];
  const float* ln2g = (const float*)d_in[5];
  const float* ln2b = (const float*)d_in[6];
  const float* wq = (const float*)d_in[7];
  const float* wk = (const float*)d_in[8];
  const float* wv = (const float*)d_in[9];
  const float* wo = (const float*)d_in[10];
  const float* w1 = (const float*)d_in[11];
  const float* b1 = (const float*)d_in[12];
  const float* w2 = (const float*)d_in[13];
  const float* b2 = (const float*)d_in[14];
  const float* cwk = (const float*)d_in[15];
  const float* cwq = (const float*)d_in[17];

  float* out_t = (float*)d_out;
  float* out_self = out_t + 2097152;
  float* out_cross = out_self + 33554432;

  char* ws = (char*)d_ws;
  size_t off = 0;
  auto alloc = [&](size_t bytes) -> void* {
    void* p = ws + off; off = (off + bytes + 255) & ~(size_t)255; return p;
  };
  short* xb   = (short*)alloc(2097152ull * 2);   // LN1(tokens) bf16
  short* tokb = (short*)alloc(2097152ull * 2);   // tokens bf16
  float* tf   = (float*)alloc(2097152ull * 4);   // t after attention, f32
  short* tb   = (short*)alloc(2097152ull * 2);   // final t bf16
  short* yb   = (short*)alloc(2097152ull * 2);   // LN2(t) bf16
  short* h1b  = (short*)alloc(8388608ull * 2);   // gelu hidden
  short* qb   = (short*)alloc(16777216ull * 2);  // qn [B,H,L,D]; later tM
  short* vtb  = (short*)alloc(16777216ull * 2);  // v^T [B,H,D,L]
  short* Eb   = (short*)alloc(33554432ull * 2);  // exp(logit-8) bf16
  short* comb = (short*)alloc(16777216ull * 2);  // ctx [B,L,H*D]
  short* Wstk = (short*)alloc(4194304ull * 2);   // [NhT(4096); wv(4096)] x 512
  short* Mstk = (short*)alloc(2097152ull * 2);   // MhT [4096,512]
  short* wop  = (short*)alloc(2097152ull * 2);
  short* w1b  = (short*)alloc(1048576ull * 2);
  short* w2b  = (short*)alloc(1048576ull * 2);
  short* QT   = (short*)alloc(4194304ull * 2);   // [wqT(8); cwqT(8)] heads
  short* KT   = (short*)alloc(4194304ull * 2);   // [wkT(8); cwkT(8)] heads

  // 1. prep: LN1+tokb | wv/w1/w2 cvt | wo permute | q/k weight transposes
  prep<<<24576, 256, 0, stream>>>(tokens, ln1g, ln1b, wv, w1, w2, wo,
                                  wq, wk, cwq, cwk,
                                  xb, tokb, Wstk + 2097152, w1b, w2b, wop, QT, KT);
  // 2. NhT (z<8 -> Wstk) and MhT (z>=8 -> Mstk), full-grid 128-tiles
  gemm_nt<8, 128><<<dim3(4, 4, 16), 256, 0, stream>>>(KT, QT, 512,
      nullptr, nullptr, nullptr, Wstk, Mstk);
  // 3. qn + v: [4096,512] x [8192,512]^T
  gemm256<0><<<dim3(32, 16, 1), 512, 0, stream>>>(xb, Wstk, 512, 0, 0,
      nullptr, qb, vtb, nullptr, nullptr);
  // 4. self E: qn . x^T, triangular 256-tiles x 32 heads
  gemm256<1><<<dim3(10, 1, 32), 512, 0, stream>>>(qb, xb, 512, 524288, 524288,
      nullptr, Eb, nullptr, nullptr, nullptr);
  // 5. PV (+fused rownorm: ctx*inv -> comb, W -> out_self)
  gemm256<2><<<dim3(2, 4, 32), 512, 0, stream>>>(Eb, vtb, 1024, 1048576, 524288,
      out_self, comb, nullptr, nullptr, nullptr);
  // 6. sa + residual
  gemm_nt<3, 64><<<dim3(8, 32, 1), 256, 0, stream>>>(comb, wop, 4096,
      tokens, nullptr, tf, nullptr, nullptr);
  // 7. LN2
  ln_rows<<<4096, 256, 0, stream>>>(tf, ln2g, ln2b, yb);
  // 8. ffn1 + gelu
  gemm_nt<4, 128><<<dim3(16, 32, 1), 256, 0, stream>>>(yb, w1b, 512,
      b1, nullptr, nullptr, h1b, nullptr);
  // 9. ffn2 + residuals
  gemm_nt<5, 64><<<dim3(8, 32, 1), 256, 0, stream>>>(h1b, w2b, 2048,
      b2, tf, out_t, tb, nullptr);
  // 10. tM = t * MhT (reuse qb)
  gemm256<6><<<dim3(16, 16, 1), 512, 0, stream>>>(tb, Mstk, 512, 0, 0,
      nullptr, qb, nullptr, tb, Mstk);
  // 11. cross E: tM . tokens^T
  gemm256<7><<<dim3(4, 4, 32), 512, 0, stream>>>(qb, tokb, 512, 524288, 524288,
      nullptr, Eb, nullptr, nullptr, nullptr);
  // 12. cross W = E/sum -> d_out
  rownorm<<<8192, 256, 0, stream>>>(Eb, out_cross);
}

// Round 8
// 610.001 us; speedup vs baseline: 1.1877x; 1.1877x over previous
//
#include <hip/hip_runtime.h>
#include <hip/hip_bf16.h>

// ---------------------------------------------------------------------------
// TransformerDecoderLayer on MI355X. bf16 MFMA, f32 accumulate.
// R8: fix R7's uncoalesced fused-W epilogue (lane-blocked -> flat coalesced
// float4 loop). Everything else from R7 retained: prep consolidation,
// full-grid Nh/Mh build, in-register PV row sums. 12 dispatches.
// ---------------------------------------------------------------------------

typedef __attribute__((ext_vector_type(4))) float f32x4;
typedef __attribute__((ext_vector_type(8))) short bf16x8;

#define SCALE 0.04419417382415922f   // 1/sqrt(512)

__device__ __forceinline__ short f2bf(float f) {
  __hip_bfloat16 h = __float2bfloat16(f);
  short s; __builtin_memcpy(&s, &h, 2); return s;
}
__device__ __forceinline__ float bf2f(short s) {
  unsigned int u = ((unsigned int)(unsigned short)s) << 16;
  float f; __builtin_memcpy(&f, &u, 4); return f;
}

__device__ __forceinline__ void gload16(const void* g, void* lds) {
  __builtin_amdgcn_global_load_lds(
      (const __attribute__((address_space(1))) unsigned int*)g,
      (__attribute__((address_space(3))) unsigned int*)lds, 16, 0, 0);
}

// ---------------- block reductions ----------------
__device__ __forceinline__ float block_sum(float v, float* sm) {
  #pragma unroll
  for (int o = 1; o < 64; o <<= 1) v += __shfl_xor(v, o, 64);
  int w = threadIdx.x >> 6;
  if ((threadIdx.x & 63) == 0) sm[w] = v;
  __syncthreads();
  float r = sm[0] + sm[1] + sm[2] + sm[3];
  __syncthreads();
  return r;
}

// ---------------- prep: LN1+tokb | cvt wv/w1/w2 | permute_wo | transpose ----
__global__ __launch_bounds__(256) void prep(
    const float* __restrict__ tokens, const float* __restrict__ ln1g,
    const float* __restrict__ ln1b,
    const float* __restrict__ wv, const float* __restrict__ w1,
    const float* __restrict__ w2, const float* __restrict__ wo,
    const float* __restrict__ wq, const float* __restrict__ wk,
    const float* __restrict__ cwq, const float* __restrict__ cwk,
    short* __restrict__ xb, short* __restrict__ tokb,
    short* __restrict__ wvb, short* __restrict__ w1b, short* __restrict__ w2b,
    short* __restrict__ wop, short* __restrict__ QT, short* __restrict__ KT) {
  __shared__ float sm[4];
  __shared__ float tile[32][33];
  const int bid = blockIdx.x;
  if (bid < 4096) {
    size_t row = bid;
    const float2 v = reinterpret_cast<const float2*>(tokens + row * 512)[threadIdx.x];
    short2 ro; ro.x = f2bf(v.x); ro.y = f2bf(v.y);
    reinterpret_cast<short2*>(tokb + row * 512)[threadIdx.x] = ro;
    float mu = block_sum(v.x + v.y, sm) * (1.0f / 512.0f);
    float dx = v.x - mu, dy = v.y - mu;
    float var = block_sum(dx * dx + dy * dy, sm) * (1.0f / 512.0f);
    float rs = rsqrtf(var + 1e-6f);
    int c = threadIdx.x * 2;
    short2 o;
    o.x = f2bf(dx * rs * ln1g[c] + ln1b[c]);
    o.y = f2bf(dy * rs * ln1g[c + 1] + ln1b[c + 1]);
    reinterpret_cast<short2*>(xb + row * 512)[threadIdx.x] = o;
  } else if (bid < 8192) {
    int i = (bid - 4096) * 256 + threadIdx.x;
    const float* src; short* dst; int k;
    if (i < 524288)      { src = wv; dst = wvb; k = i; }
    else if (i < 786432) { src = w1; dst = w1b; k = i - 524288; }
    else                 { src = w2; dst = w2b; k = i - 786432; }
    float4 v = reinterpret_cast<const float4*>(src)[k];
    short4 o; o.x = f2bf(v.x); o.y = f2bf(v.y); o.z = f2bf(v.z); o.w = f2bf(v.w);
    reinterpret_cast<short4*>(dst)[k] = o;
  } else if (bid < 16384) {
    int i = (bid - 8192) * 256 + threadIdx.x;
    int o = i >> 12, j = i & 4095;
    int h = j >> 9, d = j & 511;
    int h2 = d >> 6, e = d & 63;
    wop[i] = f2bf(wo[(o << 12) + h2 * 512 + h * 64 + e]);
  } else {
    const int idx = bid - 16384;                // 8192: 32 tensor-heads x 256 tiles
    const int z = idx >> 8, t = z >> 3, h = z & 7;
    const int tl = idx & 255, by = tl >> 4, bx = tl & 15;
    const float* in = (t == 0) ? wq : (t == 1) ? wk : (t == 2) ? cwq : cwk;
    short* out = (t == 0) ? QT : (t == 1) ? KT
               : (t == 2) ? (QT + 8ull * 262144) : (KT + 8ull * 262144);
    const int tx = threadIdx.x & 31, ty = threadIdx.x >> 5;
    const size_t base = (size_t)h * 262144;
    #pragma unroll
    for (int r = 0; r < 4; ++r) {
      const int o = by * 32 + ty + r * 8;
      tile[ty + r * 8][tx] = in[base + (size_t)o * 512 + bx * 32 + tx];
    }
    __syncthreads();
    #pragma unroll
    for (int r = 0; r < 4; ++r) {
      const int d = bx * 32 + ty + r * 8;
      out[base + (size_t)d * 512 + by * 32 + tx] = f2bf(tile[tx][ty + r * 8]);
    }
  }
}

// ---------------- layernorm (LN2 only) ----------------
__global__ __launch_bounds__(256) void ln_rows(const float* __restrict__ in,
    const float* __restrict__ gw, const float* __restrict__ bw,
    short* __restrict__ out) {
  __shared__ float sm[4];
  size_t row = blockIdx.x;
  const float2 v = reinterpret_cast<const float2*>(in + row * 512)[threadIdx.x];
  float mu = block_sum(v.x + v.y, sm) * (1.0f / 512.0f);
  float dx = v.x - mu, dy = v.y - mu;
  float var = block_sum(dx * dx + dy * dy, sm) * (1.0f / 512.0f);
  float rs = rsqrtf(var + 1e-6f);
  int c = threadIdx.x * 2;
  short2 o;
  o.x = f2bf(dx * rs * gw[c] + bw[c]);
  o.y = f2bf(dy * rs * gw[c + 1] + bw[c + 1]);
  reinterpret_cast<short2*>(out + row * 512)[threadIdx.x] = o;
}

// ---------------- rownorm (cross only): W = E / rowsum(E) ------------------
__global__ __launch_bounds__(256) void rownorm(const short* __restrict__ E,
                                               float* __restrict__ W) {
  const int wv = threadIdx.x >> 6, l = threadIdx.x & 63;
  const size_t row = (size_t)blockIdx.x * 4 + wv;
  const short* ep = E + row * 1024;
  float s = 0.f;
  #pragma unroll
  for (int c = 0; c < 2; ++c) {
    bf16x8 v = *reinterpret_cast<const bf16x8*>(ep + c * 512 + l * 8);
    #pragma unroll
    for (int j = 0; j < 8; ++j) s += bf2f(v[j]);
  }
  #pragma unroll
  for (int o = 1; o < 64; o <<= 1) s += __shfl_xor(s, o, 64);
  const float inv = 1.0f / s;
  float* wp = W + row * 1024;
  #pragma unroll
  for (int c = 0; c < 4; ++c) {
    const int c0 = c * 256 + l * 4;
    short4 v = *reinterpret_cast<const short4*>(ep + c0);
    float4 o4;
    o4.x = bf2f(v.x) * inv; o4.y = bf2f(v.y) * inv;
    o4.z = bf2f(v.z) * inv; o4.w = bf2f(v.w) * inv;
    *reinterpret_cast<float4*>(wp + c0) = o4;
  }
}

// ===========================================================================
// 8-phase pipelined 256x256 GEMM.
// EPI 0: x*[NhT;wv] -> qn [B,H,L,D], v^T [B,H,D,L]
// EPI 1: self E=exp(qn.x^T*SCALE-8) bf16, triangular; B per-batch stride
// EPI 2: PV; in-register row sums -> inv; ctx*inv -> comb; W=E*inv (coalesced)
// EPI 6: tM = t*MhT
// EPI 7: cross E bf16; B per-batch stride
// ===========================================================================
#define STAGEH(ldsoff, gbase, grow0, kcol0) do {                               \
    const int rr_ = tid >> 3;                                                  \
    const int cc_ = ((tid & 7) ^ (rr_ & 7)) << 3;                              \
    gload16((gbase) + (size_t)((grow0) + rr_) * K + (kcol0) + cc_,             \
            &sh[(ldsoff) + (tid >> 6) * 512]);                                 \
    gload16((gbase) + (size_t)((grow0) + 64 + rr_) * K + (kcol0) + cc_,        \
            &sh[(ldsoff) + 4096 + (tid >> 6) * 512]);                          \
  } while (0)

#define READ_A(g) do {                                                         \
    _Pragma("unroll")                                                          \
    for (int mi = 0; mi < 4; ++mi) {                                           \
      const int row_ = wm * 64 + mi * 16 + lr;                                 \
      _Pragma("unroll")                                                        \
      for (int ks = 0; ks < 2; ++ks)                                           \
        a[mi][ks] = *reinterpret_cast<const bf16x8*>(                          \
            &sh[abase + (g) * 8192 + row_ * 64 + ((((ks << 2) + kh) ^ sx) << 3)]); \
    } } while (0)

#define READ_B(dst, n) do {                                                    \
    _Pragma("unroll")                                                          \
    for (int njj = 0; njj < 2; ++njj) {                                        \
      const int row_ = wn * 32 + njj * 16 + lr;                                \
      _Pragma("unroll")                                                        \
      for (int ks = 0; ks < 2; ++ks)                                           \
        dst[njj][ks] = *reinterpret_cast<const bf16x8*>(                       \
            &sh[bbase + (n) * 8192 + row_ * 64 + ((((ks << 2) + kh) ^ sx) << 3)]); \
    } } while (0)

#define MFMA_PH(g, n, bb) do {                                                 \
    __builtin_amdgcn_s_setprio(1);                                             \
    _Pragma("unroll")                                                          \
    for (int mi = 0; mi < 4; ++mi)                                             \
      _Pragma("unroll")                                                        \
      for (int njj = 0; njj < 2; ++njj)                                        \
        _Pragma("unroll")                                                      \
        for (int ks = 0; ks < 2; ++ks)                                         \
          acc[(g) * 4 + mi][(n) * 2 + njj] =                                   \
              __builtin_amdgcn_mfma_f32_16x16x32_bf16(                         \
                  bb[njj][ks], a[mi][ks], acc[(g) * 4 + mi][(n) * 2 + njj],    \
                  0, 0, 0);                                                    \
    __builtin_amdgcn_s_setprio(0); } while (0)

template<int EPI>
__global__ __launch_bounds__(512, 1) void gemm256(
    const short* __restrict__ A, const short* __restrict__ Bw,
    int K, long long sA, long long sB,
    float* __restrict__ fout, short* __restrict__ bout,
    short* __restrict__ bout3,
    const short* __restrict__ A2, const short* __restrict__ B2) {
  __shared__ short sh[65536];               // 128 KiB
  const int tid = threadIdx.x;
  const int w = tid >> 6, l = tid & 63;
  const int wm = w >> 2, wn = w & 3;        // 2 M-waves x 4 N-waves
  const int lr = l & 15, kh = l >> 4;
  const int sx = lr & 7;
  int bx = blockIdx.x, by = blockIdx.y;
  const int z = blockIdx.z;
  if constexpr (EPI == 1) {                 // triangular: bx<=by
    int idx = blockIdx.x;
    by = 0;
    while ((by + 1) * (by + 2) / 2 <= idx) ++by;
    bx = idx - by * (by + 1) / 2;
  }
  const int bm = by * 256, bn = bx * 256;
  const short* Ab; const short* Bb;
  if constexpr (EPI == 1 || EPI == 7) {
    Ab = A + (size_t)z * sA;                 // per-(b,h)
    Bb = Bw + (size_t)(z >> 3) * sB;         // per-batch (shared across heads)
  } else if constexpr (EPI == 6) {
    Ab = z ? A2 : A; Bb = z ? B2 : Bw;
  } else {
    Ab = A + (size_t)z * sA; Bb = Bw + (size_t)z * sB;
  }

  const int kend = (EPI == 2) ? (bm + 256) : K;
  const int NT = kend >> 6;

  f32x4 acc[8][4];
  #pragma unroll
  for (int mf = 0; mf < 8; ++mf)
    #pragma unroll
    for (int nf = 0; nf < 4; ++nf) acc[mf][nf] = (f32x4){0.f, 0.f, 0.f, 0.f};
  float rs[8] = {0.f, 0.f, 0.f, 0.f, 0.f, 0.f, 0.f, 0.f};

  // prologue: tile0 all 4 halves, then tile1 {A0, B0, A1}
  STAGEH(0,     Ab, bm,       0);
  STAGEH(8192,  Ab, bm + 128, 0);
  STAGEH(32768, Bb, bn,       0);
  STAGEH(40960, Bb, bn + 128, 0);
  if (NT > 1) {
    STAGEH(16384, Ab, bm,       64);
    STAGEH(49152, Bb, bn,       64);
    STAGEH(24576, Ab, bm + 128, 64);
    asm volatile("s_waitcnt vmcnt(6)" ::: "memory");
  } else {
    asm volatile("s_waitcnt vmcnt(0)" ::: "memory");
  }
  __builtin_amdgcn_s_barrier();

  bf16x8 a[4][2], b0[2][2], b1[2][2];

  for (int t = 0; t < NT; ++t) {
    const int cb = t & 1;
    const int abase = cb * 16384;
    const int bbase = 32768 + cb * 16384;
    const int b2base = 32768 + (cb ^ 1) * 16384;
    const int kc1 = (t + 1) << 6, kc2 = (t + 2) << 6;
    const bool m1 = (t + 1 < NT), m2 = (t + 2 < NT);

    // ---- ph0 ----
    READ_A(0);
    READ_B(b0, 0);
    if (m1) STAGEH(b2base + 8192, Bb, bn + 128, kc1);
    __builtin_amdgcn_s_barrier();
    asm volatile("s_waitcnt lgkmcnt(0)" ::: "memory");
    __builtin_amdgcn_sched_barrier(0);
    MFMA_PH(0, 0, b0);
    if constexpr (EPI == 2) {               // row-sum of A-g0
      #pragma unroll
      for (int mi = 0; mi < 4; ++mi)
        #pragma unroll
        for (int ks = 0; ks < 2; ++ks)
          #pragma unroll
          for (int jj = 0; jj < 8; ++jj) rs[mi] += bf2f(a[mi][ks][jj]);
    }
    __builtin_amdgcn_s_barrier();

    // ---- ph1 ----
    READ_B(b1, 1);
    if (m2) STAGEH(abase, Ab, bm, kc2);
    __builtin_amdgcn_s_barrier();
    asm volatile("s_waitcnt lgkmcnt(0)" ::: "memory");
    __builtin_amdgcn_sched_barrier(0);
    MFMA_PH(0, 1, b1);
    __builtin_amdgcn_s_barrier();

    // ---- ph2 ----
    READ_A(1);
    if (m2) STAGEH(bbase, Bb, bn, kc2);
    __builtin_amdgcn_s_barrier();
    asm volatile("s_waitcnt lgkmcnt(0)" ::: "memory");
    __builtin_amdgcn_sched_barrier(0);
    MFMA_PH(1, 0, b0);
    if constexpr (EPI == 2) {               // row-sum of A-g1
      #pragma unroll
      for (int mi = 0; mi < 4; ++mi)
        #pragma unroll
        for (int ks = 0; ks < 2; ++ks)
          #pragma unroll
          for (int jj = 0; jj < 8; ++jj) rs[4 + mi] += bf2f(a[mi][ks][jj]);
    }
    __builtin_amdgcn_s_barrier();

    // ---- ph3 ----
    if (m2) STAGEH(abase + 8192, Ab, bm + 128, kc2);
    __builtin_amdgcn_s_barrier();
    __builtin_amdgcn_sched_barrier(0);
    MFMA_PH(1, 1, b1);
    if (m1) {
      if (m2) asm volatile("s_waitcnt vmcnt(6)" ::: "memory");
      else    asm volatile("s_waitcnt vmcnt(0)" ::: "memory");
      __builtin_amdgcn_s_barrier();
    }
  }

  float* inv_sm = reinterpret_cast<float*>(sh);
  if constexpr (EPI == 2) {
    #pragma unroll
    for (int mf = 0; mf < 8; ++mf) {
      rs[mf] += __shfl_xor(rs[mf], 16, 64);
      rs[mf] += __shfl_xor(rs[mf], 32, 64);
      rs[mf] = 1.0f / rs[mf];
    }
    if (wn == 0 && kh == 0) {
      #pragma unroll
      for (int mf = 0; mf < 8; ++mf)
        inv_sm[(mf >> 2) * 128 + wm * 64 + (mf & 3) * 16 + lr] = rs[mf];
    }
  }

  // Epilogue. Swapped-operand C layout: lane owns row (lr field) x 4 cols.
  #pragma unroll
  for (int mf = 0; mf < 8; ++mf) {
    const int grow = bm + (mf >> 2) * 128 + wm * 64 + (mf & 3) * 16 + lr;
    #pragma unroll
    for (int nf = 0; nf < 4; ++nf) {
      const int gcol0 = bn + (nf >> 1) * 128 + wn * 32 + (nf & 1) * 16 + kh * 4;
      const float v0 = acc[mf][nf][0], v1 = acc[mf][nf][1];
      const float v2 = acc[mf][nf][2], v3 = acc[mf][nf][3];
      if constexpr (EPI == 0) {
        const int b = grow >> 10, lw = grow & 1023;
        if (bn < 4096) {    // qn [B,H,L,D]
          const int h = gcol0 >> 9, o = gcol0 & 511;
          *reinterpret_cast<short4*>(&bout[(((size_t)(b * 8 + h)) * 1024 + lw) * 512 + o]) =
              make_short4(f2bf(v0), f2bf(v1), f2bf(v2), f2bf(v3));
        } else {            // v^T [B,H,D,L]
          const int n2 = gcol0 - 4096, h = n2 >> 9, o = n2 & 511;
          const size_t base = ((size_t)(b * 8 + h)) * 512;
          bout3[(base + o + 0) * 1024 + lw] = f2bf(v0);
          bout3[(base + o + 1) * 1024 + lw] = f2bf(v1);
          bout3[(base + o + 2) * 1024 + lw] = f2bf(v2);
          bout3[(base + o + 3) * 1024 + lw] = f2bf(v3);
        }
      } else if constexpr (EPI == 1) {
        short4 o;
        o.x = (gcol0 + 0 > grow) ? (short)0 : f2bf(__expf(v0 * SCALE - 8.0f));
        o.y = (gcol0 + 1 > grow) ? (short)0 : f2bf(__expf(v1 * SCALE - 8.0f));
        o.z = (gcol0 + 2 > grow) ? (short)0 : f2bf(__expf(v2 * SCALE - 8.0f));
        o.w = (gcol0 + 3 > grow) ? (short)0 : f2bf(__expf(v3 * SCALE - 8.0f));
        *reinterpret_cast<short4*>(&bout[(size_t)z * 1048576 + (size_t)grow * 1024 + gcol0]) = o;
      } else if constexpr (EPI == 2) {
        const float inv = rs[mf];
        const int b = z >> 3, h = z & 7;
        *reinterpret_cast<short4*>(&bout[((size_t)(b * 1024 + grow)) * 4096 + h * 512 + gcol0]) =
            make_short4(f2bf(v0 * inv), f2bf(v1 * inv), f2bf(v2 * inv), f2bf(v3 * inv));
      } else if constexpr (EPI == 6) {
        const int b = grow >> 10, lw = grow & 1023;
        const int h = gcol0 >> 9, o = gcol0 & 511;
        *reinterpret_cast<short4*>(&bout[(((size_t)(b * 8 + h)) * 1024 + lw) * 512 + o]) =
            make_short4(f2bf(v0), f2bf(v1), f2bf(v2), f2bf(v3));
      } else if constexpr (EPI == 7) {
        short4 o;
        o.x = f2bf(__expf(v0 * SCALE - 8.0f));
        o.y = f2bf(__expf(v1 * SCALE - 8.0f));
        o.z = f2bf(__expf(v2 * SCALE - 8.0f));
        o.w = f2bf(__expf(v3 * SCALE - 8.0f));
        *reinterpret_cast<short4*>(&bout[(size_t)z * 1048576 + (size_t)grow * 1024 + gcol0]) = o;
      }
    }
  }

  if constexpr (EPI == 2) {
    // W = E * inv for rows [bm,bm+256), cols [bx*512,(bx+1)*512).
    // COALESCED: consecutive lanes -> consecutive float4 (128 threads/row).
    __syncthreads();
    const int colb = bx * 512;
    float* wbase = fout + (size_t)z * 1048576;
    for (int it = 0; it < 64; ++it) {
      const int idx = it * 2048 + tid * 4;
      const int r = idx >> 9;
      const int c = colb + (idx & 511);
      const float inv = inv_sm[r];
      float4 o4;
      if (c < kend) {
        short4 e = *reinterpret_cast<const short4*>(Ab + (size_t)(bm + r) * 1024 + c);
        o4.x = bf2f(e.x) * inv; o4.y = bf2f(e.y) * inv;
        o4.z = bf2f(e.z) * inv; o4.w = bf2f(e.w) * inv;
      } else { o4.x = o4.y = o4.z = o4.w = 0.f; }
      *reinterpret_cast<float4*>(wbase + (size_t)(bm + r) * 1024 + c) = o4;
    }
  }
}

// ---------------- 128-tile kernel ----------------
// EPI 3: sa   EPI 4: ffn1-gelu   EPI 5: ffn2   EPI 8: NhT/MhT build
template<int EPI, int BN>
__global__ __launch_bounds__(256, 2) void gemm_nt(
    const short* __restrict__ A, const short* __restrict__ Bw,
    int K, const float* __restrict__ fin, const float* __restrict__ fin2,
    float* __restrict__ fout, short* __restrict__ bout,
    short* __restrict__ bout2) {
  constexpr int NJ = BN / 32;
  __shared__ short As[128 * 32];
  __shared__ short Bs[BN * 32];
  const int tid = threadIdx.x;
  const int w = tid >> 6, l = tid & 63;
  const int wr = w >> 1, wc = w & 1;
  const int lr = l & 15, kh = l >> 4;
  const int bm = blockIdx.y * 128, bn = blockIdx.x * BN;
  const int ar = w * 16 + (l >> 2);
  const int ac = (l & 3) * 8;
  const short* Ab = A; const short* Bb = Bw;
  if constexpr (EPI == 8) {
    Ab = A + (size_t)blockIdx.z * 262144;
    Bb = Bw + (size_t)blockIdx.z * 262144;
  }

  f32x4 acc[4][NJ];
  #pragma unroll
  for (int i = 0; i < 4; ++i)
    #pragma unroll
    for (int j = 0; j < NJ; ++j) acc[i][j] = (f32x4){0.f, 0.f, 0.f, 0.f};

  for (int k0 = 0; k0 < K; k0 += 32) {
    #pragma unroll
    for (int c = 0; c < 2; ++c)
      gload16(Ab + (size_t)(bm + c * 64 + ar) * K + k0 + ac, &As[c * 2048 + w * 512]);
    #pragma unroll
    for (int c = 0; c < BN / 64; ++c)
      gload16(Bb + (size_t)(bn + c * 64 + ar) * K + k0 + ac, &Bs[c * 2048 + w * 512]);
    __syncthreads();
    bf16x8 af[4], bfr[NJ];
    #pragma unroll
    for (int i = 0; i < 4; ++i)
      af[i] = *reinterpret_cast<const bf16x8*>(&As[(wr * 64 + i * 16 + lr) * 32 + kh * 8]);
    #pragma unroll
    for (int j = 0; j < NJ; ++j)
      bfr[j] = *reinterpret_cast<const bf16x8*>(&Bs[(wc * (BN / 2) + j * 16 + lr) * 32 + kh * 8]);
    #pragma unroll
    for (int i = 0; i < 4; ++i)
      #pragma unroll
      for (int j = 0; j < NJ; ++j)
        acc[i][j] = __builtin_amdgcn_mfma_f32_16x16x32_bf16(bfr[j], af[i], acc[i][j], 0, 0, 0);
    __syncthreads();
  }

  #pragma unroll
  for (int i = 0; i < 4; ++i) {
    const int grow = bm + wr * 64 + i * 16 + lr;
    #pragma unroll
    for (int j = 0; j < NJ; ++j) {
      const int gcol0 = bn + wc * (BN / 2) + j * 16 + kh * 4;
      const float v0 = acc[i][j][0], v1 = acc[i][j][1];
      const float v2 = acc[i][j][2], v3 = acc[i][j][3];
      if constexpr (EPI == 3) {
        const size_t idx = (size_t)grow * 512 + gcol0;
        const float4 t4 = *reinterpret_cast<const float4*>(&fin[idx]);
        float4 f; f.x = t4.x + v0; f.y = t4.y + v1; f.z = t4.z + v2; f.w = t4.w + v3;
        *reinterpret_cast<float4*>(&fout[idx]) = f;
      } else if constexpr (EPI == 4) {
        const float4 b4 = *reinterpret_cast<const float4*>(&fin[gcol0]);
        const float x0 = v0 + b4.x, x1 = v1 + b4.y, x2 = v2 + b4.z, x3 = v3 + b4.w;
        const float g0 = 0.5f * x0 * (1.0f + erff(x0 * 0.70710678118654752f));
        const float g1 = 0.5f * x1 * (1.0f + erff(x1 * 0.70710678118654752f));
        const float g2 = 0.5f * x2 * (1.0f + erff(x2 * 0.70710678118654752f));
        const float g3 = 0.5f * x3 * (1.0f + erff(x3 * 0.70710678118654752f));
        *reinterpret_cast<short4*>(&bout[(size_t)grow * 2048 + gcol0]) =
            make_short4(f2bf(g0), f2bf(g1), f2bf(g2), f2bf(g3));
      } else if constexpr (EPI == 5) {
        const size_t idx = (size_t)grow * 512 + gcol0;
        const float4 a4 = *reinterpret_cast<const float4*>(&fin2[idx]);
        const float4 b4 = *reinterpret_cast<const float4*>(&fin[gcol0]);
        float4 f;
        f.x = a4.x + v0 + b4.x; f.y = a4.y + v1 + b4.y;
        f.z = a4.z + v2 + b4.z; f.w = a4.w + v3 + b4.w;
        *reinterpret_cast<float4*>(&fout[idx]) = f;
        *reinterpret_cast<short4*>(&bout[idx]) =
            make_short4(f2bf(f.x), f2bf(f.y), f2bf(f.z), f2bf(f.w));
      } else if constexpr (EPI == 8) {
        short* outp = ((blockIdx.z < 8) ? bout : bout2) +
                      (size_t)(blockIdx.z & 7) * 262144;
        *reinterpret_cast<short4*>(&outp[(size_t)grow * 512 + gcol0]) =
            make_short4(f2bf(v0), f2bf(v1), f2bf(v2), f2bf(v3));
      }
    }
  }
}

// ---------------------------------------------------------------------------
extern "C" void kernel_launch(void* const* d_in, const int* in_sizes, int n_in,
                              void* d_out, int out_size, void* d_ws, size_t ws_size,
                              hipStream_t stream) {
  const float* tokens = (const float*)d_in[0];
  const float* ln1g = (const float*)d_in[3];
  const float* ln1b = (const float*)d_in[4];
  const float* ln2g = (const float*)d_in[5];
  const float* ln2b = (const float*)d_in[6];
  const float* wq = (const float*)d_in[7];
  const float* wk = (const float*)d_in[8];
  const float* wv = (const float*)d_in[9];
  const float* wo = (const float*)d_in[10];
  const float* w1 = (const float*)d_in[11];
  const float* b1 = (const float*)d_in[12];
  const float* w2 = (const float*)d_in[13];
  const float* b2 = (const float*)d_in[14];
  const float* cwk = (const float*)d_in[15];
  const float* cwq = (const float*)d_in[17];

  float* out_t = (float*)d_out;
  float* out_self = out_t + 2097152;
  float* out_cross = out_self + 33554432;

  char* ws = (char*)d_ws;
  size_t off = 0;
  auto alloc = [&](size_t bytes) -> void* {
    void* p = ws + off; off = (off + bytes + 255) & ~(size_t)255; return p;
  };
  short* xb   = (short*)alloc(2097152ull * 2);
  short* tokb = (short*)alloc(2097152ull * 2);
  float* tf   = (float*)alloc(2097152ull * 4);
  short* tb   = (short*)alloc(2097152ull * 2);
  short* yb   = (short*)alloc(2097152ull * 2);
  short* h1b  = (short*)alloc(8388608ull * 2);
  short* qb   = (short*)alloc(16777216ull * 2);
  short* vtb  = (short*)alloc(16777216ull * 2);
  short* Eb   = (short*)alloc(33554432ull * 2);
  short* comb = (short*)alloc(16777216ull * 2);
  short* Wstk = (short*)alloc(4194304ull * 2);
  short* Mstk = (short*)alloc(2097152ull * 2);
  short* wop  = (short*)alloc(2097152ull * 2);
  short* w1b  = (short*)alloc(1048576ull * 2);
  short* w2b  = (short*)alloc(1048576ull * 2);
  short* QT   = (short*)alloc(4194304ull * 2);
  short* KT   = (short*)alloc(4194304ull * 2);

  // 1. prep
  prep<<<24576, 256, 0, stream>>>(tokens, ln1g, ln1b, wv, w1, w2, wo,
                                  wq, wk, cwq, cwk,
                                  xb, tokb, Wstk + 2097152, w1b, w2b, wop, QT, KT);
  // 2. NhT (z<8 -> Wstk) and MhT (z>=8 -> Mstk)
  gemm_nt<8, 128><<<dim3(4, 4, 16), 256, 0, stream>>>(KT, QT, 512,
      nullptr, nullptr, nullptr, Wstk, Mstk);
  // 3. qn + v
  gemm256<0><<<dim3(32, 16, 1), 512, 0, stream>>>(xb, Wstk, 512, 0, 0,
      nullptr, qb, vtb, nullptr, nullptr);
  // 4. self E
  gemm256<1><<<dim3(10, 1, 32), 512, 0, stream>>>(qb, xb, 512, 524288, 524288,
      nullptr, Eb, nullptr, nullptr, nullptr);
  // 5. PV (+fused rownorm, coalesced W write)
  gemm256<2><<<dim3(2, 4, 32), 512, 0, stream>>>(Eb, vtb, 1024, 1048576, 524288,
      out_self, comb, nullptr, nullptr, nullptr);
  // 6. sa + residual
  gemm_nt<3, 64><<<dim3(8, 32, 1), 256, 0, stream>>>(comb, wop, 4096,
      tokens, nullptr, tf, nullptr, nullptr);
  // 7. LN2
  ln_rows<<<4096, 256, 0, stream>>>(tf, ln2g, ln2b, yb);
  // 8. ffn1 + gelu
  gemm_nt<4, 128><<<dim3(16, 32, 1), 256, 0, stream>>>(yb, w1b, 512,
      b1, nullptr, nullptr, h1b, nullptr);
  // 9. ffn2 + residuals
  gemm_nt<5, 64><<<dim3(8, 32, 1), 256, 0, stream>>>(h1b, w2b, 2048,
      b2, tf, out_t, tb, nullptr);
  // 10. tM = t * MhT
  gemm256<6><<<dim3(16, 16, 1), 512, 0, stream>>>(tb, Mstk, 512, 0, 0,
      nullptr, qb, nullptr, tb, Mstk);
  // 11. cross E
  gemm256<7><<<dim3(4, 4, 32), 512, 0, stream>>>(qb, tokb, 512, 524288, 524288,
      nullptr, Eb, nullptr, nullptr, nullptr);
  // 12. cross W = E/sum -> d_out
  rownorm<<<8192, 256, 0, stream>>>(Eb, out_cross);
}

// Round 9
// 548.118 us; speedup vs baseline: 1.3218x; 1.1129x over previous
//
#include <hip/hip_runtime.h>
#include <hip/hip_bf16.h>

// ---------------------------------------------------------------------------
// TransformerDecoderLayer on MI355X. bf16 MFMA, f32 accumulate.
// R9: revert PV-fusion (R7/R8 regression) to R6's separate causal rownorm;
// keep prep consolidation + full-grid NhT/MhT build. 13 dispatches.
// ---------------------------------------------------------------------------

typedef __attribute__((ext_vector_type(4))) float f32x4;
typedef __attribute__((ext_vector_type(8))) short bf16x8;

#define SCALE 0.04419417382415922f   // 1/sqrt(512)

__device__ __forceinline__ short f2bf(float f) {
  __hip_bfloat16 h = __float2bfloat16(f);
  short s; __builtin_memcpy(&s, &h, 2); return s;
}
__device__ __forceinline__ float bf2f(short s) {
  unsigned int u = ((unsigned int)(unsigned short)s) << 16;
  float f; __builtin_memcpy(&f, &u, 4); return f;
}

__device__ __forceinline__ void gload16(const void* g, void* lds) {
  __builtin_amdgcn_global_load_lds(
      (const __attribute__((address_space(1))) unsigned int*)g,
      (__attribute__((address_space(3))) unsigned int*)lds, 16, 0, 0);
}

// ---------------- block reductions ----------------
__device__ __forceinline__ float block_sum(float v, float* sm) {
  #pragma unroll
  for (int o = 1; o < 64; o <<= 1) v += __shfl_xor(v, o, 64);
  int w = threadIdx.x >> 6;
  if ((threadIdx.x & 63) == 0) sm[w] = v;
  __syncthreads();
  float r = sm[0] + sm[1] + sm[2] + sm[3];
  __syncthreads();
  return r;
}

// ---------------- prep: LN1+tokb | cvt wv/w1/w2 | permute_wo | transpose ----
__global__ __launch_bounds__(256) void prep(
    const float* __restrict__ tokens, const float* __restrict__ ln1g,
    const float* __restrict__ ln1b,
    const float* __restrict__ wv, const float* __restrict__ w1,
    const float* __restrict__ w2, const float* __restrict__ wo,
    const float* __restrict__ wq, const float* __restrict__ wk,
    const float* __restrict__ cwq, const float* __restrict__ cwk,
    short* __restrict__ xb, short* __restrict__ tokb,
    short* __restrict__ wvb, short* __restrict__ w1b, short* __restrict__ w2b,
    short* __restrict__ wop, short* __restrict__ QT, short* __restrict__ KT) {
  __shared__ float sm[4];
  __shared__ float tile[32][33];
  const int bid = blockIdx.x;
  if (bid < 4096) {
    size_t row = bid;
    const float2 v = reinterpret_cast<const float2*>(tokens + row * 512)[threadIdx.x];
    short2 ro; ro.x = f2bf(v.x); ro.y = f2bf(v.y);
    reinterpret_cast<short2*>(tokb + row * 512)[threadIdx.x] = ro;
    float mu = block_sum(v.x + v.y, sm) * (1.0f / 512.0f);
    float dx = v.x - mu, dy = v.y - mu;
    float var = block_sum(dx * dx + dy * dy, sm) * (1.0f / 512.0f);
    float rs = rsqrtf(var + 1e-6f);
    int c = threadIdx.x * 2;
    short2 o;
    o.x = f2bf(dx * rs * ln1g[c] + ln1b[c]);
    o.y = f2bf(dy * rs * ln1g[c + 1] + ln1b[c + 1]);
    reinterpret_cast<short2*>(xb + row * 512)[threadIdx.x] = o;
  } else if (bid < 8192) {
    int i = (bid - 4096) * 256 + threadIdx.x;
    const float* src; short* dst; int k;
    if (i < 524288)      { src = wv; dst = wvb; k = i; }
    else if (i < 786432) { src = w1; dst = w1b; k = i - 524288; }
    else                 { src = w2; dst = w2b; k = i - 786432; }
    float4 v = reinterpret_cast<const float4*>(src)[k];
    short4 o; o.x = f2bf(v.x); o.y = f2bf(v.y); o.z = f2bf(v.z); o.w = f2bf(v.w);
    reinterpret_cast<short4*>(dst)[k] = o;
  } else if (bid < 16384) {
    int i = (bid - 8192) * 256 + threadIdx.x;
    int o = i >> 12, j = i & 4095;
    int h = j >> 9, d = j & 511;
    int h2 = d >> 6, e = d & 63;
    wop[i] = f2bf(wo[(o << 12) + h2 * 512 + h * 64 + e]);
  } else {
    const int idx = bid - 16384;                // 8192: 32 tensor-heads x 256 tiles
    const int z = idx >> 8, t = z >> 3, h = z & 7;
    const int tl = idx & 255, by = tl >> 4, bx = tl & 15;
    const float* in = (t == 0) ? wq : (t == 1) ? wk : (t == 2) ? cwq : cwk;
    short* out = (t == 0) ? QT : (t == 1) ? KT
               : (t == 2) ? (QT + 8ull * 262144) : (KT + 8ull * 262144);
    const int tx = threadIdx.x & 31, ty = threadIdx.x >> 5;
    const size_t base = (size_t)h * 262144;
    #pragma unroll
    for (int r = 0; r < 4; ++r) {
      const int o = by * 32 + ty + r * 8;
      tile[ty + r * 8][tx] = in[base + (size_t)o * 512 + bx * 32 + tx];
    }
    __syncthreads();
    #pragma unroll
    for (int r = 0; r < 4; ++r) {
      const int d = bx * 32 + ty + r * 8;
      out[base + (size_t)d * 512 + by * 32 + tx] = f2bf(tile[tx][ty + r * 8]);
    }
  }
}

// ---------------- layernorm (LN2 only) ----------------
__global__ __launch_bounds__(256) void ln_rows(const float* __restrict__ in,
    const float* __restrict__ gw, const float* __restrict__ bw,
    short* __restrict__ out) {
  __shared__ float sm[4];
  size_t row = blockIdx.x;
  const float2 v = reinterpret_cast<const float2*>(in + row * 512)[threadIdx.x];
  float mu = block_sum(v.x + v.y, sm) * (1.0f / 512.0f);
  float dx = v.x - mu, dy = v.y - mu;
  float var = block_sum(dx * dx + dy * dy, sm) * (1.0f / 512.0f);
  float rs = rsqrtf(var + 1e-6f);
  int c = threadIdx.x * 2;
  short2 o;
  o.x = f2bf(dx * rs * gw[c] + bw[c]);
  o.y = f2bf(dy * rs * gw[c + 1] + bw[c + 1]);
  reinterpret_cast<short2*>(out + row * 512)[threadIdx.x] = o;
}

// ---------------- rownorm: W = E / rowsum(E), one wave per row -------------
// CAUSAL: E cols >= live_end (tile-rounded) were never written — never read;
// W there = 0. Stores inv for PV's epilogue scaling.
template<int CAUSAL>
__global__ __launch_bounds__(256) void rownorm(const short* __restrict__ E,
    float* __restrict__ W, float* __restrict__ inv_out) {
  const int wv = threadIdx.x >> 6, l = threadIdx.x & 63;
  const size_t row = (size_t)blockIdx.x * 4 + wv;
  const int r = (int)(row & 1023);
  const int live_end = CAUSAL ? (((r >> 8) + 1) << 8) : 1024;
  const short* ep = E + row * 1024;
  float s = 0.f;
  #pragma unroll
  for (int c = 0; c < 2; ++c) {
    const int c0 = c * 512 + l * 8;
    if (c0 < live_end) {
      bf16x8 v = *reinterpret_cast<const bf16x8*>(ep + c0);
      #pragma unroll
      for (int j = 0; j < 8; ++j) s += bf2f(v[j]);
    }
  }
  #pragma unroll
  for (int o = 1; o < 64; o <<= 1) s += __shfl_xor(s, o, 64);
  const float inv = 1.0f / s;
  if (CAUSAL && l == 0) inv_out[row] = inv;
  float* wp = W + row * 1024;
  #pragma unroll
  for (int c = 0; c < 4; ++c) {
    const int c0 = c * 256 + l * 4;
    float4 o4;
    if (c0 < live_end) {
      short4 v = *reinterpret_cast<const short4*>(ep + c0);
      o4.x = bf2f(v.x) * inv; o4.y = bf2f(v.y) * inv;
      o4.z = bf2f(v.z) * inv; o4.w = bf2f(v.w) * inv;
    } else { o4.x = o4.y = o4.z = o4.w = 0.f; }
    *reinterpret_cast<float4*>(wp + c0) = o4;
  }
}

// ===========================================================================
// 8-phase pipelined 256x256 GEMM.
// EPI 0: x*[NhT;wv] -> qn [B,H,L,D], v^T [B,H,D,L]
// EPI 1: self E=exp(qn.x^T*SCALE-8) bf16, triangular; B per-batch stride
// EPI 2: PV x inv_sum (fin) -> comb
// EPI 6: tM = t*MhT
// EPI 7: cross E bf16; B per-batch stride
// ===========================================================================
#define STAGEH(ldsoff, gbase, grow0, kcol0) do {                               \
    const int rr_ = tid >> 3;                                                  \
    const int cc_ = ((tid & 7) ^ (rr_ & 7)) << 3;                              \
    gload16((gbase) + (size_t)((grow0) + rr_) * K + (kcol0) + cc_,             \
            &sh[(ldsoff) + (tid >> 6) * 512]);                                 \
    gload16((gbase) + (size_t)((grow0) + 64 + rr_) * K + (kcol0) + cc_,        \
            &sh[(ldsoff) + 4096 + (tid >> 6) * 512]);                          \
  } while (0)

#define READ_A(g) do {                                                         \
    _Pragma("unroll")                                                          \
    for (int mi = 0; mi < 4; ++mi) {                                           \
      const int row_ = wm * 64 + mi * 16 + lr;                                 \
      _Pragma("unroll")                                                        \
      for (int ks = 0; ks < 2; ++ks)                                           \
        a[mi][ks] = *reinterpret_cast<const bf16x8*>(                          \
            &sh[abase + (g) * 8192 + row_ * 64 + ((((ks << 2) + kh) ^ sx) << 3)]); \
    } } while (0)

#define READ_B(dst, n) do {                                                    \
    _Pragma("unroll")                                                          \
    for (int njj = 0; njj < 2; ++njj) {                                        \
      const int row_ = wn * 32 + njj * 16 + lr;                                \
      _Pragma("unroll")                                                        \
      for (int ks = 0; ks < 2; ++ks)                                           \
        dst[njj][ks] = *reinterpret_cast<const bf16x8*>(                       \
            &sh[bbase + (n) * 8192 + row_ * 64 + ((((ks << 2) + kh) ^ sx) << 3)]); \
    } } while (0)

#define MFMA_PH(g, n, bb) do {                                                 \
    __builtin_amdgcn_s_setprio(1);                                             \
    _Pragma("unroll")                                                          \
    for (int mi = 0; mi < 4; ++mi)                                             \
      _Pragma("unroll")                                                        \
      for (int njj = 0; njj < 2; ++njj)                                        \
        _Pragma("unroll")                                                      \
        for (int ks = 0; ks < 2; ++ks)                                         \
          acc[(g) * 4 + mi][(n) * 2 + njj] =                                   \
              __builtin_amdgcn_mfma_f32_16x16x32_bf16(                         \
                  bb[njj][ks], a[mi][ks], acc[(g) * 4 + mi][(n) * 2 + njj],    \
                  0, 0, 0);                                                    \
    __builtin_amdgcn_s_setprio(0); } while (0)

template<int EPI>
__global__ __launch_bounds__(512, 1) void gemm256(
    const short* __restrict__ A, const short* __restrict__ Bw,
    int K, long long sA, long long sB,
    const float* __restrict__ fin,
    float* __restrict__ fout, short* __restrict__ bout,
    short* __restrict__ bout3,
    const short* __restrict__ A2, const short* __restrict__ B2) {
  __shared__ short sh[65536];               // 128 KiB
  const int tid = threadIdx.x;
  const int w = tid >> 6, l = tid & 63;
  const int wm = w >> 2, wn = w & 3;        // 2 M-waves x 4 N-waves
  const int lr = l & 15, kh = l >> 4;
  const int sx = lr & 7;
  int bx = blockIdx.x, by = blockIdx.y;
  const int z = blockIdx.z;
  if constexpr (EPI == 1) {                 // triangular: bx<=by
    int idx = blockIdx.x;
    by = 0;
    while ((by + 1) * (by + 2) / 2 <= idx) ++by;
    bx = idx - by * (by + 1) / 2;
  }
  const int bm = by * 256, bn = bx * 256;
  const short* Ab; const short* Bb;
  if constexpr (EPI == 1 || EPI == 7) {
    Ab = A + (size_t)z * sA;                 // per-(b,h)
    Bb = Bw + (size_t)(z >> 3) * sB;         // per-batch (shared across heads)
  } else if constexpr (EPI == 6) {
    Ab = z ? A2 : A; Bb = z ? B2 : Bw;
  } else {
    Ab = A + (size_t)z * sA; Bb = Bw + (size_t)z * sB;
  }

  const int kend = (EPI == 2) ? (bm + 256) : K;
  const int NT = kend >> 6;

  f32x4 acc[8][4];
  #pragma unroll
  for (int mf = 0; mf < 8; ++mf)
    #pragma unroll
    for (int nf = 0; nf < 4; ++nf) acc[mf][nf] = (f32x4){0.f, 0.f, 0.f, 0.f};

  // prologue: tile0 all 4 halves, then tile1 {A0, B0, A1}
  STAGEH(0,     Ab, bm,       0);
  STAGEH(8192,  Ab, bm + 128, 0);
  STAGEH(32768, Bb, bn,       0);
  STAGEH(40960, Bb, bn + 128, 0);
  if (NT > 1) {
    STAGEH(16384, Ab, bm,       64);
    STAGEH(49152, Bb, bn,       64);
    STAGEH(24576, Ab, bm + 128, 64);
    asm volatile("s_waitcnt vmcnt(6)" ::: "memory");
  } else {
    asm volatile("s_waitcnt vmcnt(0)" ::: "memory");
  }
  __builtin_amdgcn_s_barrier();

  bf16x8 a[4][2], b0[2][2], b1[2][2];

  for (int t = 0; t < NT; ++t) {
    const int cb = t & 1;
    const int abase = cb * 16384;
    const int bbase = 32768 + cb * 16384;
    const int b2base = 32768 + (cb ^ 1) * 16384;
    const int kc1 = (t + 1) << 6, kc2 = (t + 2) << 6;
    const bool m1 = (t + 1 < NT), m2 = (t + 2 < NT);

    // ---- ph0 ----
    READ_A(0);
    READ_B(b0, 0);
    if (m1) STAGEH(b2base + 8192, Bb, bn + 128, kc1);
    __builtin_amdgcn_s_barrier();
    asm volatile("s_waitcnt lgkmcnt(0)" ::: "memory");
    __builtin_amdgcn_sched_barrier(0);
    MFMA_PH(0, 0, b0);
    __builtin_amdgcn_s_barrier();

    // ---- ph1 ----
    READ_B(b1, 1);
    if (m2) STAGEH(abase, Ab, bm, kc2);
    __builtin_amdgcn_s_barrier();
    asm volatile("s_waitcnt lgkmcnt(0)" ::: "memory");
    __builtin_amdgcn_sched_barrier(0);
    MFMA_PH(0, 1, b1);
    __builtin_amdgcn_s_barrier();

    // ---- ph2 ----
    READ_A(1);
    if (m2) STAGEH(bbase, Bb, bn, kc2);
    __builtin_amdgcn_s_barrier();
    asm volatile("s_waitcnt lgkmcnt(0)" ::: "memory");
    __builtin_amdgcn_sched_barrier(0);
    MFMA_PH(1, 0, b0);
    __builtin_amdgcn_s_barrier();

    // ---- ph3 ----
    if (m2) STAGEH(abase + 8192, Ab, bm + 128, kc2);
    __builtin_amdgcn_s_barrier();
    __builtin_amdgcn_sched_barrier(0);
    MFMA_PH(1, 1, b1);
    if (m1) {
      if (m2) asm volatile("s_waitcnt vmcnt(6)" ::: "memory");
      else    asm volatile("s_waitcnt vmcnt(0)" ::: "memory");
      __builtin_amdgcn_s_barrier();
    }
  }

  // Epilogue. Swapped-operand C layout: lane owns row (lr field) x 4 cols.
  #pragma unroll
  for (int mf = 0; mf < 8; ++mf) {
    const int grow = bm + (mf >> 2) * 128 + wm * 64 + (mf & 3) * 16 + lr;
    #pragma unroll
    for (int nf = 0; nf < 4; ++nf) {
      const int gcol0 = bn + (nf >> 1) * 128 + wn * 32 + (nf & 1) * 16 + kh * 4;
      const float v0 = acc[mf][nf][0], v1 = acc[mf][nf][1];
      const float v2 = acc[mf][nf][2], v3 = acc[mf][nf][3];
      if constexpr (EPI == 0) {
        const int b = grow >> 10, lw = grow & 1023;
        if (bn < 4096) {    // qn [B,H,L,D]
          const int h = gcol0 >> 9, o = gcol0 & 511;
          *reinterpret_cast<short4*>(&bout[(((size_t)(b * 8 + h)) * 1024 + lw) * 512 + o]) =
              make_short4(f2bf(v0), f2bf(v1), f2bf(v2), f2bf(v3));
        } else {            // v^T [B,H,D,L]
          const int n2 = gcol0 - 4096, h = n2 >> 9, o = n2 & 511;
          const size_t base = ((size_t)(b * 8 + h)) * 512;
          bout3[(base + o + 0) * 1024 + lw] = f2bf(v0);
          bout3[(base + o + 1) * 1024 + lw] = f2bf(v1);
          bout3[(base + o + 2) * 1024 + lw] = f2bf(v2);
          bout3[(base + o + 3) * 1024 + lw] = f2bf(v3);
        }
      } else if constexpr (EPI == 1) {
        short4 o;
        o.x = (gcol0 + 0 > grow) ? (short)0 : f2bf(__expf(v0 * SCALE - 8.0f));
        o.y = (gcol0 + 1 > grow) ? (short)0 : f2bf(__expf(v1 * SCALE - 8.0f));
        o.z = (gcol0 + 2 > grow) ? (short)0 : f2bf(__expf(v2 * SCALE - 8.0f));
        o.w = (gcol0 + 3 > grow) ? (short)0 : f2bf(__expf(v3 * SCALE - 8.0f));
        *reinterpret_cast<short4*>(&bout[(size_t)z * 1048576 + (size_t)grow * 1024 + gcol0]) = o;
      } else if constexpr (EPI == 2) {
        const float inv = fin[(size_t)z * 1024 + grow];
        const int b = z >> 3, h = z & 7;
        *reinterpret_cast<short4*>(&bout[((size_t)(b * 1024 + grow)) * 4096 + h * 512 + gcol0]) =
            make_short4(f2bf(v0 * inv), f2bf(v1 * inv), f2bf(v2 * inv), f2bf(v3 * inv));
      } else if constexpr (EPI == 6) {
        const int b = grow >> 10, lw = grow & 1023;
        const int h = gcol0 >> 9, o = gcol0 & 511;
        *reinterpret_cast<short4*>(&bout[(((size_t)(b * 8 + h)) * 1024 + lw) * 512 + o]) =
            make_short4(f2bf(v0), f2bf(v1), f2bf(v2), f2bf(v3));
      } else if constexpr (EPI == 7) {
        short4 o;
        o.x = f2bf(__expf(v0 * SCALE - 8.0f));
        o.y = f2bf(__expf(v1 * SCALE - 8.0f));
        o.z = f2bf(__expf(v2 * SCALE - 8.0f));
        o.w = f2bf(__expf(v3 * SCALE - 8.0f));
        *reinterpret_cast<short4*>(&bout[(size_t)z * 1048576 + (size_t)grow * 1024 + gcol0]) = o;
      }
    }
  }
}

// ---------------- 128-tile kernel ----------------
// EPI 3: sa   EPI 4: ffn1-gelu   EPI 5: ffn2   EPI 8: NhT/MhT build
template<int EPI, int BN>
__global__ __launch_bounds__(256, 2) void gemm_nt(
    const short* __restrict__ A, const short* __restrict__ Bw,
    int K, const float* __restrict__ fin, const float* __restrict__ fin2,
    float* __restrict__ fout, short* __restrict__ bout,
    short* __restrict__ bout2) {
  constexpr int NJ = BN / 32;
  __shared__ short As[128 * 32];
  __shared__ short Bs[BN * 32];
  const int tid = threadIdx.x;
  const int w = tid >> 6, l = tid & 63;
  const int wr = w >> 1, wc = w & 1;
  const int lr = l & 15, kh = l >> 4;
  const int bm = blockIdx.y * 128, bn = blockIdx.x * BN;
  const int ar = w * 16 + (l >> 2);
  const int ac = (l & 3) * 8;
  const short* Ab = A; const short* Bb = Bw;
  if constexpr (EPI == 8) {
    Ab = A + (size_t)blockIdx.z * 262144;
    Bb = Bw + (size_t)blockIdx.z * 262144;
  }

  f32x4 acc[4][NJ];
  #pragma unroll
  for (int i = 0; i < 4; ++i)
    #pragma unroll
    for (int j = 0; j < NJ; ++j) acc[i][j] = (f32x4){0.f, 0.f, 0.f, 0.f};

  for (int k0 = 0; k0 < K; k0 += 32) {
    #pragma unroll
    for (int c = 0; c < 2; ++c)
      gload16(Ab + (size_t)(bm + c * 64 + ar) * K + k0 + ac, &As[c * 2048 + w * 512]);
    #pragma unroll
    for (int c = 0; c < BN / 64; ++c)
      gload16(Bb + (size_t)(bn + c * 64 + ar) * K + k0 + ac, &Bs[c * 2048 + w * 512]);
    __syncthreads();
    bf16x8 af[4], bfr[NJ];
    #pragma unroll
    for (int i = 0; i < 4; ++i)
      af[i] = *reinterpret_cast<const bf16x8*>(&As[(wr * 64 + i * 16 + lr) * 32 + kh * 8]);
    #pragma unroll
    for (int j = 0; j < NJ; ++j)
      bfr[j] = *reinterpret_cast<const bf16x8*>(&Bs[(wc * (BN / 2) + j * 16 + lr) * 32 + kh * 8]);
    #pragma unroll
    for (int i = 0; i < 4; ++i)
      #pragma unroll
      for (int j = 0; j < NJ; ++j)
        acc[i][j] = __builtin_amdgcn_mfma_f32_16x16x32_bf16(bfr[j], af[i], acc[i][j], 0, 0, 0);
    __syncthreads();
  }

  #pragma unroll
  for (int i = 0; i < 4; ++i) {
    const int grow = bm + wr * 64 + i * 16 + lr;
    #pragma unroll
    for (int j = 0; j < NJ; ++j) {
      const int gcol0 = bn + wc * (BN / 2) + j * 16 + kh * 4;
      const float v0 = acc[i][j][0], v1 = acc[i][j][1];
      const float v2 = acc[i][j][2], v3 = acc[i][j][3];
      if constexpr (EPI == 3) {
        const size_t idx = (size_t)grow * 512 + gcol0;
        const float4 t4 = *reinterpret_cast<const float4*>(&fin[idx]);
        float4 f; f.x = t4.x + v0; f.y = t4.y + v1; f.z = t4.z + v2; f.w = t4.w + v3;
        *reinterpret_cast<float4*>(&fout[idx]) = f;
      } else if constexpr (EPI == 4) {
        const float4 b4 = *reinterpret_cast<const float4*>(&fin[gcol0]);
        const float x0 = v0 + b4.x, x1 = v1 + b4.y, x2 = v2 + b4.z, x3 = v3 + b4.w;
        const float g0 = 0.5f * x0 * (1.0f + erff(x0 * 0.70710678118654752f));
        const float g1 = 0.5f * x1 * (1.0f + erff(x1 * 0.70710678118654752f));
        const float g2 = 0.5f * x2 * (1.0f + erff(x2 * 0.70710678118654752f));
        const float g3 = 0.5f * x3 * (1.0f + erff(x3 * 0.70710678118654752f));
        *reinterpret_cast<short4*>(&bout[(size_t)grow * 2048 + gcol0]) =
            make_short4(f2bf(g0), f2bf(g1), f2bf(g2), f2bf(g3));
      } else if constexpr (EPI == 5) {
        const size_t idx = (size_t)grow * 512 + gcol0;
        const float4 a4 = *reinterpret_cast<const float4*>(&fin2[idx]);
        const float4 b4 = *reinterpret_cast<const float4*>(&fin[gcol0]);
        float4 f;
        f.x = a4.x + v0 + b4.x; f.y = a4.y + v1 + b4.y;
        f.z = a4.z + v2 + b4.z; f.w = a4.w + v3 + b4.w;
        *reinterpret_cast<float4*>(&fout[idx]) = f;
        *reinterpret_cast<short4*>(&bout[idx]) =
            make_short4(f2bf(f.x), f2bf(f.y), f2bf(f.z), f2bf(f.w));
      } else if constexpr (EPI == 8) {
        short* outp = ((blockIdx.z < 8) ? bout : bout2) +
                      (size_t)(blockIdx.z & 7) * 262144;
        *reinterpret_cast<short4*>(&outp[(size_t)grow * 512 + gcol0]) =
            make_short4(f2bf(v0), f2bf(v1), f2bf(v2), f2bf(v3));
      }
    }
  }
}

// ---------------------------------------------------------------------------
extern "C" void kernel_launch(void* const* d_in, const int* in_sizes, int n_in,
                              void* d_out, int out_size, void* d_ws, size_t ws_size,
                              hipStream_t stream) {
  const float* tokens = (const float*)d_in[0];
  const float* ln1g = (const float*)d_in[3];
  const float* ln1b = (const float*)d_in[4];
  const float* ln2g = (const float*)d_in[5];
  const float* ln2b = (const float*)d_in[6];
  const float* wq = (const float*)d_in[7];
  const float* wk = (const float*)d_in[8];
  const float* wv = (const float*)d_in[9];
  const float* wo = (const float*)d_in[10];
  const float* w1 = (const float*)d_in[11];
  const float* b1 = (const float*)d_in[12];
  const float* w2 = (const float*)d_in[13];
  const float* b2 = (const float*)d_in[14];
  const float* cwk = (const float*)d_in[15];
  const float* cwq = (const float*)d_in[17];

  float* out_t = (float*)d_out;
  float* out_self = out_t + 2097152;
  float* out_cross = out_self + 33554432;

  char* ws = (char*)d_ws;
  size_t off = 0;
  auto alloc = [&](size_t bytes) -> void* {
    void* p = ws + off; off = (off + bytes + 255) & ~(size_t)255; return p;
  };
  short* xb   = (short*)alloc(2097152ull * 2);
  short* tokb = (short*)alloc(2097152ull * 2);
  float* tf   = (float*)alloc(2097152ull * 4);
  short* tb   = (short*)alloc(2097152ull * 2);
  short* yb   = (short*)alloc(2097152ull * 2);
  short* h1b  = (short*)alloc(8388608ull * 2);
  short* qb   = (short*)alloc(16777216ull * 2);
  short* vtb  = (short*)alloc(16777216ull * 2);
  short* Eb   = (short*)alloc(33554432ull * 2);
  short* comb = (short*)alloc(16777216ull * 2);
  short* Wstk = (short*)alloc(4194304ull * 2);
  short* Mstk = (short*)alloc(2097152ull * 2);
  short* wop  = (short*)alloc(2097152ull * 2);
  short* w1b  = (short*)alloc(1048576ull * 2);
  short* w2b  = (short*)alloc(1048576ull * 2);
  short* QT   = (short*)alloc(4194304ull * 2);
  short* KT   = (short*)alloc(4194304ull * 2);
  float* inv_s = (float*)alloc(32768ull * 4);

  // 1. prep
  prep<<<24576, 256, 0, stream>>>(tokens, ln1g, ln1b, wv, w1, w2, wo,
                                  wq, wk, cwq, cwk,
                                  xb, tokb, Wstk + 2097152, w1b, w2b, wop, QT, KT);
  // 2. NhT (z<8 -> Wstk) and MhT (z>=8 -> Mstk)
  gemm_nt<8, 128><<<dim3(4, 4, 16), 256, 0, stream>>>(KT, QT, 512,
      nullptr, nullptr, nullptr, Wstk, Mstk);
  // 3. qn + v
  gemm256<0><<<dim3(32, 16, 1), 512, 0, stream>>>(xb, Wstk, 512, 0, 0,
      nullptr, nullptr, qb, vtb, nullptr, nullptr);
  // 4. self E
  gemm256<1><<<dim3(10, 1, 32), 512, 0, stream>>>(qb, xb, 512, 524288, 524288,
      nullptr, nullptr, Eb, nullptr, nullptr, nullptr);
  // 5. self W = E/sum -> d_out (dense), store inv sums
  rownorm<1><<<8192, 256, 0, stream>>>(Eb, out_self, inv_s);
  // 6. PV on raw E, scale by inv in epilogue; K truncated per row-tile
  gemm256<2><<<dim3(2, 4, 32), 512, 0, stream>>>(Eb, vtb, 1024, 1048576, 524288,
      inv_s, nullptr, comb, nullptr, nullptr, nullptr);
  // 7. sa + residual
  gemm_nt<3, 64><<<dim3(8, 32, 1), 256, 0, stream>>>(comb, wop, 4096,
      tokens, nullptr, tf, nullptr, nullptr);
  // 8. LN2
  ln_rows<<<4096, 256, 0, stream>>>(tf, ln2g, ln2b, yb);
  // 9. ffn1 + gelu
  gemm_nt<4, 128><<<dim3(16, 32, 1), 256, 0, stream>>>(yb, w1b, 512,
      b1, nullptr, nullptr, h1b, nullptr);
  // 10. ffn2 + residuals
  gemm_nt<5, 64><<<dim3(8, 32, 1), 256, 0, stream>>>(h1b, w2b, 2048,
      b2, tf, out_t, tb, nullptr);
  // 11. tM = t * MhT
  gemm256<6><<<dim3(16, 16, 1), 512, 0, stream>>>(tb, Mstk, 512, 0, 0,
      nullptr, nullptr, qb, nullptr, tb, Mstk);
  // 12. cross E
  gemm256<7><<<dim3(4, 4, 32), 512, 0, stream>>>(qb, tokb, 512, 524288, 524288,
      nullptr, nullptr, Eb, nullptr, nullptr, nullptr);
  // 13. cross W = E/sum -> d_out
  rownorm<0><<<8192, 256, 0, stream>>>(Eb, out_cross, nullptr);
}

// Round 10
// 477.377 us; speedup vs baseline: 1.5177x; 1.1482x over previous
//
#include <hip/hip_runtime.h>
#include <hip/hip_bf16.h>

// ---------------------------------------------------------------------------
// TransformerDecoderLayer on MI355X. bf16 MFMA, f32 accumulate.
// R10: value-path fold. U_h = wo_h*wv_h built per head; x*U^T replaces the v
// projection; PV+sa collapse into one kernel (h summed in K-loop, causal K
// truncation), consuming P = E*inv written in-place by rownorm. Partial-h
// planes summed in a 3-input LN2. 12 dispatches.
// ---------------------------------------------------------------------------

typedef __attribute__((ext_vector_type(4))) float f32x4;
typedef __attribute__((ext_vector_type(8))) short bf16x8;

#define SCALE 0.04419417382415922f   // 1/sqrt(512)

__device__ __forceinline__ short f2bf(float f) {
  __hip_bfloat16 h = __float2bfloat16(f);
  short s; __builtin_memcpy(&s, &h, 2); return s;
}
__device__ __forceinline__ float bf2f(short s) {
  unsigned int u = ((unsigned int)(unsigned short)s) << 16;
  float f; __builtin_memcpy(&f, &u, 4); return f;
}

__device__ __forceinline__ void gload16(const void* g, void* lds) {
  __builtin_amdgcn_global_load_lds(
      (const __attribute__((address_space(1))) unsigned int*)g,
      (__attribute__((address_space(3))) unsigned int*)lds, 16, 0, 0);
}

// ---------------- block reductions ----------------
__device__ __forceinline__ float block_sum(float v, float* sm) {
  #pragma unroll
  for (int o = 1; o < 64; o <<= 1) v += __shfl_xor(v, o, 64);
  int w = threadIdx.x >> 6;
  if ((threadIdx.x & 63) == 0) sm[w] = v;
  __syncthreads();
  float r = sm[0] + sm[1] + sm[2] + sm[3];
  __syncthreads();
  return r;
}

// ---------------- prep: LN1+tokb | cvt w1/w2 | permute_wo | 5 transposes ----
// [0,4096): LN1 rows; [4096,6144): cvt; [6144,14336): permute_wo;
// [14336,24576): 32x32 transposes of wq/wk/cwq/cwk/wv.
__global__ __launch_bounds__(256) void prep(
    const float* __restrict__ tokens, const float* __restrict__ ln1g,
    const float* __restrict__ ln1b,
    const float* __restrict__ w1, const float* __restrict__ w2,
    const float* __restrict__ wo,
    const float* __restrict__ wq, const float* __restrict__ wk,
    const float* __restrict__ cwq, const float* __restrict__ cwk,
    const float* __restrict__ wv,
    short* __restrict__ xb, short* __restrict__ tokb,
    short* __restrict__ w1b, short* __restrict__ w2b,
    short* __restrict__ wop, short* __restrict__ QT, short* __restrict__ KT,
    short* __restrict__ WVT) {
  __shared__ float sm[4];
  __shared__ float tile[32][33];
  const int bid = blockIdx.x;
  if (bid < 4096) {
    size_t row = bid;
    const float2 v = reinterpret_cast<const float2*>(tokens + row * 512)[threadIdx.x];
    short2 ro; ro.x = f2bf(v.x); ro.y = f2bf(v.y);
    reinterpret_cast<short2*>(tokb + row * 512)[threadIdx.x] = ro;
    float mu = block_sum(v.x + v.y, sm) * (1.0f / 512.0f);
    float dx = v.x - mu, dy = v.y - mu;
    float var = block_sum(dx * dx + dy * dy, sm) * (1.0f / 512.0f);
    float rs = rsqrtf(var + 1e-6f);
    int c = threadIdx.x * 2;
    short2 o;
    o.x = f2bf(dx * rs * ln1g[c] + ln1b[c]);
    o.y = f2bf(dy * rs * ln1g[c + 1] + ln1b[c + 1]);
    reinterpret_cast<short2*>(xb + row * 512)[threadIdx.x] = o;
  } else if (bid < 6144) {
    int i = (bid - 4096) * 256 + threadIdx.x;   // 524288 float4 jobs
    const float* src; short* dst; int k;
    if (i < 262144) { src = w1; dst = w1b; k = i; }
    else            { src = w2; dst = w2b; k = i - 262144; }
    float4 v = reinterpret_cast<const float4*>(src)[k];
    short4 o; o.x = f2bf(v.x); o.y = f2bf(v.y); o.z = f2bf(v.z); o.w = f2bf(v.w);
    reinterpret_cast<short4*>(dst)[k] = o;
  } else if (bid < 14336) {
    int i = (bid - 6144) * 256 + threadIdx.x;   // wo permute, 2,097,152 elems
    int o = i >> 12, j = i & 4095;
    int h = j >> 9, d = j & 511;
    int h2 = d >> 6, e = d & 63;
    wop[i] = f2bf(wo[(o << 12) + h2 * 512 + h * 64 + e]);
  } else {
    const int idx = bid - 14336;                // 10240: 40 tensor-heads x 256
    const int z = idx >> 8, t = z >> 3, h = z & 7;
    const int tl = idx & 255, by = tl >> 4, bx = tl & 15;
    const float* in = (t == 0) ? wq : (t == 1) ? wk : (t == 2) ? cwq
                    : (t == 3) ? cwk : wv;
    short* out = (t == 0) ? QT : (t == 1) ? KT
               : (t == 2) ? (QT + 2097152) : (t == 3) ? (KT + 2097152) : WVT;
    const int tx = threadIdx.x & 31, ty = threadIdx.x >> 5;
    const size_t base = (size_t)h * 262144;
    #pragma unroll
    for (int r = 0; r < 4; ++r) {
      const int o = by * 32 + ty + r * 8;
      tile[ty + r * 8][tx] = in[base + (size_t)o * 512 + bx * 32 + tx];
    }
    __syncthreads();
    #pragma unroll
    for (int r = 0; r < 4; ++r) {
      const int d = bx * 32 + ty + r * 8;
      out[base + (size_t)d * 512 + by * 32 + tx] = f2bf(tile[tx][ty + r * 8]);
    }
  }
}

// ---------------- LN2 fused: t = tokens + p0 + p1 -> tf (f32) + yb (bf16) --
__global__ __launch_bounds__(256) void ln2_fuse(
    const float* __restrict__ tokens,
    const float* __restrict__ p0, const float* __restrict__ p1,
    const float* __restrict__ gw, const float* __restrict__ bw,
    float* __restrict__ tf, short* __restrict__ yb) {
  __shared__ float sm[4];
  size_t row = blockIdx.x;
  const size_t i2 = row * 256 + threadIdx.x;
  const float2 tv = reinterpret_cast<const float2*>(tokens)[i2];
  const float2 a2 = reinterpret_cast<const float2*>(p0)[i2];
  const float2 b2 = reinterpret_cast<const float2*>(p1)[i2];
  float x0 = tv.x + a2.x + b2.x, x1 = tv.y + a2.y + b2.y;
  float2 o2; o2.x = x0; o2.y = x1;
  reinterpret_cast<float2*>(tf)[i2] = o2;
  float mu = block_sum(x0 + x1, sm) * (1.0f / 512.0f);
  float dx = x0 - mu, dy = x1 - mu;
  float var = block_sum(dx * dx + dy * dy, sm) * (1.0f / 512.0f);
  float rs = rsqrtf(var + 1e-6f);
  int c = threadIdx.x * 2;
  short2 o;
  o.x = f2bf(dx * rs * gw[c] + bw[c]);
  o.y = f2bf(dy * rs * gw[c + 1] + bw[c + 1]);
  reinterpret_cast<short2*>(yb + row * 512)[threadIdx.x] = o;
}

// ---------------- rownorm: W = E/rowsum -> d_out; CAUSAL also P=bf16(W) ----
// in-place P over E is safe: each chunk's reads precede its write.
template<int CAUSAL>
__global__ __launch_bounds__(256) void rownorm(const short* __restrict__ E,
    float* __restrict__ W, short* __restrict__ pout) {
  const int wv = threadIdx.x >> 6, l = threadIdx.x & 63;
  const size_t row = (size_t)blockIdx.x * 4 + wv;
  const int r = (int)(row & 1023);
  const int live_end = CAUSAL ? (((r >> 8) + 1) << 8) : 1024;
  const short* ep = E + row * 1024;
  float s = 0.f;
  #pragma unroll
  for (int c = 0; c < 2; ++c) {
    const int c0 = c * 512 + l * 8;
    if (c0 < live_end) {
      bf16x8 v = *reinterpret_cast<const bf16x8*>(ep + c0);
      #pragma unroll
      for (int j = 0; j < 8; ++j) s += bf2f(v[j]);
    }
  }
  #pragma unroll
  for (int o = 1; o < 64; o <<= 1) s += __shfl_xor(s, o, 64);
  const float inv = 1.0f / s;
  float* wp = W + row * 1024;
  #pragma unroll
  for (int c = 0; c < 4; ++c) {
    const int c0 = c * 256 + l * 4;
    float4 o4;
    if (c0 < live_end) {
      short4 v = *reinterpret_cast<const short4*>(ep + c0);
      o4.x = bf2f(v.x) * inv; o4.y = bf2f(v.y) * inv;
      o4.z = bf2f(v.z) * inv; o4.w = bf2f(v.w) * inv;
      if (CAUSAL)
        *reinterpret_cast<short4*>(pout + row * 1024 + c0) =
            make_short4(f2bf(o4.x), f2bf(o4.y), f2bf(o4.z), f2bf(o4.w));
    } else { o4.x = o4.y = o4.z = o4.w = 0.f; }
    *reinterpret_cast<float4*>(wp + c0) = o4;
  }
}

// ===========================================================================
// 8-phase pipelined 256x256 GEMM.
// EPI 0: x*[NhT;U] -> qn [B,H,L,D], u^T [B,H,D,L]
// EPI 1: self E=exp(qn.x^T*SCALE-8) bf16, triangular; B per-batch stride
// EPI 6: tM = t*MhT
// EPI 7: cross E bf16; B per-batch stride
// ===========================================================================
#define STAGEH(ldsoff, gbase, grow0, kcol0) do {                               \
    const int rr_ = tid >> 3;                                                  \
    const int cc_ = ((tid & 7) ^ (rr_ & 7)) << 3;                              \
    gload16((gbase) + (size_t)((grow0) + rr_) * K + (kcol0) + cc_,             \
            &sh[(ldsoff) + (tid >> 6) * 512]);                                 \
    gload16((gbase) + (size_t)((grow0) + 64 + rr_) * K + (kcol0) + cc_,        \
            &sh[(ldsoff) + 4096 + (tid >> 6) * 512]);                          \
  } while (0)

#define READ_A(g) do {                                                         \
    _Pragma("unroll")                                                          \
    for (int mi = 0; mi < 4; ++mi) {                                           \
      const int row_ = wm * 64 + mi * 16 + lr;                                 \
      _Pragma("unroll")                                                        \
      for (int ks = 0; ks < 2; ++ks)                                           \
        a[mi][ks] = *reinterpret_cast<const bf16x8*>(                          \
            &sh[abase + (g) * 8192 + row_ * 64 + ((((ks << 2) + kh) ^ sx) << 3)]); \
    } } while (0)

#define READ_B(dst, n) do {                                                    \
    _Pragma("unroll")                                                          \
    for (int njj = 0; njj < 2; ++njj) {                                        \
      const int row_ = wn * 32 + njj * 16 + lr;                                \
      _Pragma("unroll")                                                        \
      for (int ks = 0; ks < 2; ++ks)                                           \
        dst[njj][ks] = *reinterpret_cast<const bf16x8*>(                       \
            &sh[bbase + (n) * 8192 + row_ * 64 + ((((ks << 2) + kh) ^ sx) << 3)]); \
    } } while (0)

#define MFMA_PH(g, n, bb) do {                                                 \
    __builtin_amdgcn_s_setprio(1);                                             \
    _Pragma("unroll")                                                          \
    for (int mi = 0; mi < 4; ++mi)                                             \
      _Pragma("unroll")                                                        \
      for (int njj = 0; njj < 2; ++njj)                                        \
        _Pragma("unroll")                                                      \
        for (int ks = 0; ks < 2; ++ks)                                         \
          acc[(g) * 4 + mi][(n) * 2 + njj] =                                   \
              __builtin_amdgcn_mfma_f32_16x16x32_bf16(                         \
                  bb[njj][ks], a[mi][ks], acc[(g) * 4 + mi][(n) * 2 + njj],    \
                  0, 0, 0);                                                    \
    __builtin_amdgcn_s_setprio(0); } while (0)

template<int EPI>
__global__ __launch_bounds__(512, 1) void gemm256(
    const short* __restrict__ A, const short* __restrict__ Bw,
    int K, long long sA, long long sB,
    float* __restrict__ fout, short* __restrict__ bout,
    short* __restrict__ bout3,
    const short* __restrict__ A2, const short* __restrict__ B2) {
  __shared__ short sh[65536];               // 128 KiB
  const int tid = threadIdx.x;
  const int w = tid >> 6, l = tid & 63;
  const int wm = w >> 2, wn = w & 3;        // 2 M-waves x 4 N-waves
  const int lr = l & 15, kh = l >> 4;
  const int sx = lr & 7;
  int bx = blockIdx.x, by = blockIdx.y;
  const int z = blockIdx.z;
  if constexpr (EPI == 1) {                 // triangular: bx<=by
    int idx = blockIdx.x;
    by = 0;
    while ((by + 1) * (by + 2) / 2 <= idx) ++by;
    bx = idx - by * (by + 1) / 2;
  }
  const int bm = by * 256, bn = bx * 256;
  const short* Ab; const short* Bb;
  if constexpr (EPI == 1 || EPI == 7) {
    Ab = A + (size_t)z * sA;                 // per-(b,h)
    Bb = Bw + (size_t)(z >> 3) * sB;         // per-batch (shared across heads)
  } else if constexpr (EPI == 6) {
    Ab = z ? A2 : A; Bb = z ? B2 : Bw;
  } else {
    Ab = A + (size_t)z * sA; Bb = Bw + (size_t)z * sB;
  }

  const int NT = K >> 6;

  f32x4 acc[8][4];
  #pragma unroll
  for (int mf = 0; mf < 8; ++mf)
    #pragma unroll
    for (int nf = 0; nf < 4; ++nf) acc[mf][nf] = (f32x4){0.f, 0.f, 0.f, 0.f};

  // prologue: tile0 all 4 halves, then tile1 {A0, B0, A1}
  STAGEH(0,     Ab, bm,       0);
  STAGEH(8192,  Ab, bm + 128, 0);
  STAGEH(32768, Bb, bn,       0);
  STAGEH(40960, Bb, bn + 128, 0);
  if (NT > 1) {
    STAGEH(16384, Ab, bm,       64);
    STAGEH(49152, Bb, bn,       64);
    STAGEH(24576, Ab, bm + 128, 64);
    asm volatile("s_waitcnt vmcnt(6)" ::: "memory");
  } else {
    asm volatile("s_waitcnt vmcnt(0)" ::: "memory");
  }
  __builtin_amdgcn_s_barrier();

  bf16x8 a[4][2], b0[2][2], b1[2][2];

  for (int t = 0; t < NT; ++t) {
    const int cb = t & 1;
    const int abase = cb * 16384;
    const int bbase = 32768 + cb * 16384;
    const int b2base = 32768 + (cb ^ 1) * 16384;
    const int kc1 = (t + 1) << 6, kc2 = (t + 2) << 6;
    const bool m1 = (t + 1 < NT), m2 = (t + 2 < NT);

    // ---- ph0 ----
    READ_A(0);
    READ_B(b0, 0);
    if (m1) STAGEH(b2base + 8192, Bb, bn + 128, kc1);
    __builtin_amdgcn_s_barrier();
    asm volatile("s_waitcnt lgkmcnt(0)" ::: "memory");
    __builtin_amdgcn_sched_barrier(0);
    MFMA_PH(0, 0, b0);
    __builtin_amdgcn_s_barrier();

    // ---- ph1 ----
    READ_B(b1, 1);
    if (m2) STAGEH(abase, Ab, bm, kc2);
    __builtin_amdgcn_s_barrier();
    asm volatile("s_waitcnt lgkmcnt(0)" ::: "memory");
    __builtin_amdgcn_sched_barrier(0);
    MFMA_PH(0, 1, b1);
    __builtin_amdgcn_s_barrier();

    // ---- ph2 ----
    READ_A(1);
    if (m2) STAGEH(bbase, Bb, bn, kc2);
    __builtin_amdgcn_s_barrier();
    asm volatile("s_waitcnt lgkmcnt(0)" ::: "memory");
    __builtin_amdgcn_sched_barrier(0);
    MFMA_PH(1, 0, b0);
    __builtin_amdgcn_s_barrier();

    // ---- ph3 ----
    if (m2) STAGEH(abase + 8192, Ab, bm + 128, kc2);
    __builtin_amdgcn_s_barrier();
    __builtin_amdgcn_sched_barrier(0);
    MFMA_PH(1, 1, b1);
    if (m1) {
      if (m2) asm volatile("s_waitcnt vmcnt(6)" ::: "memory");
      else    asm volatile("s_waitcnt vmcnt(0)" ::: "memory");
      __builtin_amdgcn_s_barrier();
    }
  }

  // Epilogue. Swapped-operand C layout: lane owns row (lr field) x 4 cols.
  #pragma unroll
  for (int mf = 0; mf < 8; ++mf) {
    const int grow = bm + (mf >> 2) * 128 + wm * 64 + (mf & 3) * 16 + lr;
    #pragma unroll
    for (int nf = 0; nf < 4; ++nf) {
      const int gcol0 = bn + (nf >> 1) * 128 + wn * 32 + (nf & 1) * 16 + kh * 4;
      const float v0 = acc[mf][nf][0], v1 = acc[mf][nf][1];
      const float v2 = acc[mf][nf][2], v3 = acc[mf][nf][3];
      if constexpr (EPI == 0) {
        const int b = grow >> 10, lw = grow & 1023;
        if (bn < 4096) {    // qn [B,H,L,D]
          const int h = gcol0 >> 9, o = gcol0 & 511;
          *reinterpret_cast<short4*>(&bout[(((size_t)(b * 8 + h)) * 1024 + lw) * 512 + o]) =
              make_short4(f2bf(v0), f2bf(v1), f2bf(v2), f2bf(v3));
        } else {            // u^T [B,H,D,L]
          const int n2 = gcol0 - 4096, h = n2 >> 9, o = n2 & 511;
          const size_t base = ((size_t)(b * 8 + h)) * 512;
          bout3[(base + o + 0) * 1024 + lw] = f2bf(v0);
          bout3[(base + o + 1) * 1024 + lw] = f2bf(v1);
          bout3[(base + o + 2) * 1024 + lw] = f2bf(v2);
          bout3[(base + o + 3) * 1024 + lw] = f2bf(v3);
        }
      } else if constexpr (EPI == 1) {
        short4 o;
        o.x = (gcol0 + 0 > grow) ? (short)0 : f2bf(__expf(v0 * SCALE - 8.0f));
        o.y = (gcol0 + 1 > grow) ? (short)0 : f2bf(__expf(v1 * SCALE - 8.0f));
        o.z = (gcol0 + 2 > grow) ? (short)0 : f2bf(__expf(v2 * SCALE - 8.0f));
        o.w = (gcol0 + 3 > grow) ? (short)0 : f2bf(__expf(v3 * SCALE - 8.0f));
        *reinterpret_cast<short4*>(&bout[(size_t)z * 1048576 + (size_t)grow * 1024 + gcol0]) = o;
      } else if constexpr (EPI == 6) {
        const int b = grow >> 10, lw = grow & 1023;
        const int h = gcol0 >> 9, o = gcol0 & 511;
        *reinterpret_cast<short4*>(&bout[(((size_t)(b * 8 + h)) * 1024 + lw) * 512 + o]) =
            make_short4(f2bf(v0), f2bf(v1), f2bf(v2), f2bf(v3));
      } else if constexpr (EPI == 7) {
        short4 o;
        o.x = f2bf(__expf(v0 * SCALE - 8.0f));
        o.y = f2bf(__expf(v1 * SCALE - 8.0f));
        o.z = f2bf(__expf(v2 * SCALE - 8.0f));
        o.w = f2bf(__expf(v3 * SCALE - 8.0f));
        *reinterpret_cast<short4*>(&bout[(size_t)z * 1048576 + (size_t)grow * 1024 + gcol0]) = o;
      }
    }
  }
}

// ---------------- 128-tile kernel ----------------
// EPI 4: ffn1-gelu   EPI 5: ffn2   EPI 8: NhT/MhT/U build (z<16: NT(KT,QT);
// z>=16: U_h = NT(wop_h [lda 4096], WVT_h))
template<int EPI, int BN>
__global__ __launch_bounds__(256, 2) void gemm_nt(
    const short* __restrict__ A, const short* __restrict__ Bw,
    int K, const float* __restrict__ fin, const float* __restrict__ fin2,
    float* __restrict__ fout, short* __restrict__ bout,
    short* __restrict__ bout2,
    const short* __restrict__ A3, const short* __restrict__ B3) {
  constexpr int NJ = BN / 32;
  __shared__ short As[128 * 32];
  __shared__ short Bs[BN * 32];
  const int tid = threadIdx.x;
  const int w = tid >> 6, l = tid & 63;
  const int wr = w >> 1, wc = w & 1;
  const int lr = l & 15, kh = l >> 4;
  const int bm = blockIdx.y * 128, bn = blockIdx.x * BN;
  const int ar = w * 16 + (l >> 2);
  const int ac = (l & 3) * 8;
  const short* Ab = A; const short* Bb = Bw;
  int lda = K;
  if constexpr (EPI == 8) {
    const int zz = blockIdx.z;
    if (zz < 16) { Ab = A + (size_t)zz * 262144; Bb = Bw + (size_t)zz * 262144; }
    else { Ab = A3 + (size_t)(zz - 16) * 512; Bb = B3 + (size_t)(zz - 16) * 262144;
           lda = 4096; }
  }

  f32x4 acc[4][NJ];
  #pragma unroll
  for (int i = 0; i < 4; ++i)
    #pragma unroll
    for (int j = 0; j < NJ; ++j) acc[i][j] = (f32x4){0.f, 0.f, 0.f, 0.f};

  for (int k0 = 0; k0 < K; k0 += 32) {
    #pragma unroll
    for (int c = 0; c < 2; ++c)
      gload16(Ab + (size_t)(bm + c * 64 + ar) * lda + k0 + ac, &As[c * 2048 + w * 512]);
    #pragma unroll
    for (int c = 0; c < BN / 64; ++c)
      gload16(Bb + (size_t)(bn + c * 64 + ar) * K + k0 + ac, &Bs[c * 2048 + w * 512]);
    __syncthreads();
    bf16x8 af[4], bfr[NJ];
    #pragma unroll
    for (int i = 0; i < 4; ++i)
      af[i] = *reinterpret_cast<const bf16x8*>(&As[(wr * 64 + i * 16 + lr) * 32 + kh * 8]);
    #pragma unroll
    for (int j = 0; j < NJ; ++j)
      bfr[j] = *reinterpret_cast<const bf16x8*>(&Bs[(wc * (BN / 2) + j * 16 + lr) * 32 + kh * 8]);
    #pragma unroll
    for (int i = 0; i < 4; ++i)
      #pragma unroll
      for (int j = 0; j < NJ; ++j)
        acc[i][j] = __builtin_amdgcn_mfma_f32_16x16x32_bf16(bfr[j], af[i], acc[i][j], 0, 0, 0);
    __syncthreads();
  }

  #pragma unroll
  for (int i = 0; i < 4; ++i) {
    const int grow = bm + wr * 64 + i * 16 + lr;
    #pragma unroll
    for (int j = 0; j < NJ; ++j) {
      const int gcol0 = bn + wc * (BN / 2) + j * 16 + kh * 4;
      const float v0 = acc[i][j][0], v1 = acc[i][j][1];
      const float v2 = acc[i][j][2], v3 = acc[i][j][3];
      if constexpr (EPI == 4) {
        const float4 b4 = *reinterpret_cast<const float4*>(&fin[gcol0]);
        const float x0 = v0 + b4.x, x1 = v1 + b4.y, x2 = v2 + b4.z, x3 = v3 + b4.w;
        const float g0 = 0.5f * x0 * (1.0f + erff(x0 * 0.70710678118654752f));
        const float g1 = 0.5f * x1 * (1.0f + erff(x1 * 0.70710678118654752f));
        const float g2 = 0.5f * x2 * (1.0f + erff(x2 * 0.70710678118654752f));
        const float g3 = 0.5f * x3 * (1.0f + erff(x3 * 0.70710678118654752f));
        *reinterpret_cast<short4*>(&bout[(size_t)grow * 2048 + gcol0]) =
            make_short4(f2bf(g0), f2bf(g1), f2bf(g2), f2bf(g3));
      } else if constexpr (EPI == 5) {
        const size_t idx = (size_t)grow * 512 + gcol0;
        const float4 a4 = *reinterpret_cast<const float4*>(&fin2[idx]);
        const float4 b4 = *reinterpret_cast<const float4*>(&fin[gcol0]);
        float4 f;
        f.x = a4.x + v0 + b4.x; f.y = a4.y + v1 + b4.y;
        f.z = a4.z + v2 + b4.z; f.w = a4.w + v3 + b4.w;
        *reinterpret_cast<float4*>(&fout[idx]) = f;
        *reinterpret_cast<short4*>(&bout[idx]) =
            make_short4(f2bf(f.x), f2bf(f.y), f2bf(f.z), f2bf(f.w));
      } else if constexpr (EPI == 8) {
        const int zz = blockIdx.z;
        short* outp = (zz < 8)  ? (bout + (size_t)zz * 262144)
                    : (zz < 16) ? (bout2 + (size_t)(zz - 8) * 262144)
                                : (bout + 2097152 + (size_t)(zz - 16) * 262144);
        *reinterpret_cast<short4*>(&outp[(size_t)grow * 512 + gcol0]) =
            make_short4(f2bf(v0), f2bf(v1), f2bf(v2), f2bf(v3));
      }
    }
  }
}

// ---------------- pv_sa: part[half] = sum_{h in half} P_bh * uT_bh^T -------
// 128x64 tiles; K-loop over 4 heads x causal-truncated k. Grid (8,8,8):
// x = N/64, y = M(batch)/128, z = b*2 + half. f32 partial planes.
__global__ __launch_bounds__(256, 2) void pv_sa(
    const short* __restrict__ P, const short* __restrict__ uT,
    float* __restrict__ part) {
  __shared__ short As[128 * 32];
  __shared__ short Bs[64 * 32];
  const int tid = threadIdx.x;
  const int w = tid >> 6, l = tid & 63;
  const int wr = w >> 1, wc = w & 1;
  const int lr = l & 15, kh = l >> 4;
  const int bn = blockIdx.x * 64;
  const int bm = blockIdx.y * 128;          // within batch
  const int b = blockIdx.z >> 1, half = blockIdx.z & 1;
  const int ar = w * 16 + (l >> 2);
  const int ac = (l & 3) * 8;
  const int kend = bm + 128;                // causal: P cols > row are 0

  f32x4 acc[4][2];
  #pragma unroll
  for (int i = 0; i < 4; ++i)
    #pragma unroll
    for (int j = 0; j < 2; ++j) acc[i][j] = (f32x4){0.f, 0.f, 0.f, 0.f};

  for (int h = half * 4; h < half * 4 + 4; ++h) {
    const short* Ab = P + ((size_t)(b * 8 + h) << 20);
    const short* Bb = uT + (size_t)(b * 8 + h) * 524288;
    for (int k0 = 0; k0 < kend; k0 += 32) {
      #pragma unroll
      for (int c = 0; c < 2; ++c)
        gload16(Ab + (size_t)(bm + c * 64 + ar) * 1024 + k0 + ac, &As[c * 2048 + w * 512]);
      gload16(Bb + (size_t)(bn + ar) * 1024 + k0 + ac, &Bs[w * 512]);
      __syncthreads();
      bf16x8 af[4], bfr[2];
      #pragma unroll
      for (int i = 0; i < 4; ++i)
        af[i] = *reinterpret_cast<const bf16x8*>(&As[(wr * 64 + i * 16 + lr) * 32 + kh * 8]);
      #pragma unroll
      for (int j = 0; j < 2; ++j)
        bfr[j] = *reinterpret_cast<const bf16x8*>(&Bs[(wc * 32 + j * 16 + lr) * 32 + kh * 8]);
      #pragma unroll
      for (int i = 0; i < 4; ++i)
        #pragma unroll
        for (int j = 0; j < 2; ++j)
          acc[i][j] = __builtin_amdgcn_mfma_f32_16x16x32_bf16(bfr[j], af[i], acc[i][j], 0, 0, 0);
      __syncthreads();
    }
  }

  float* plane = part + (size_t)half * 2097152;
  #pragma unroll
  for (int i = 0; i < 4; ++i) {
    const int grow = bm + wr * 64 + i * 16 + lr;
    #pragma unroll
    for (int j = 0; j < 2; ++j) {
      const int gcol0 = bn + wc * 32 + j * 16 + kh * 4;
      float4 f;
      f.x = acc[i][j][0]; f.y = acc[i][j][1];
      f.z = acc[i][j][2]; f.w = acc[i][j][3];
      *reinterpret_cast<float4*>(&plane[((size_t)(b * 1024 + grow)) * 512 + gcol0]) = f;
    }
  }
}

// ---------------------------------------------------------------------------
extern "C" void kernel_launch(void* const* d_in, const int* in_sizes, int n_in,
                              void* d_out, int out_size, void* d_ws, size_t ws_size,
                              hipStream_t stream) {
  const float* tokens = (const float*)d_in[0];
  const float* ln1g = (const float*)d_in[3];
  const float* ln1b = (const float*)d_in[4];
  const float* ln2g = (const float*)d_in[5];
  const float* ln2b = (const float*)d_in[6];
  const float* wq = (const float*)d_in[7];
  const float* wk = (const float*)d_in[8];
  const float* wv = (const float*)d_in[9];
  const float* wo = (const float*)d_in[10];
  const float* w1 = (const float*)d_in[11];
  const float* b1 = (const float*)d_in[12];
  const float* w2 = (const float*)d_in[13];
  const float* b2 = (const float*)d_in[14];
  const float* cwk = (const float*)d_in[15];
  const float* cwq = (const float*)d_in[17];

  float* out_t = (float*)d_out;
  float* out_self = out_t + 2097152;
  float* out_cross = out_self + 33554432;

  char* ws = (char*)d_ws;
  size_t off = 0;
  auto alloc = [&](size_t bytes) -> void* {
    void* p = ws + off; off = (off + bytes + 255) & ~(size_t)255; return p;
  };
  short* xb   = (short*)alloc(2097152ull * 2);   // LN1(tokens) bf16
  short* tokb = (short*)alloc(2097152ull * 2);   // tokens bf16
  float* tf   = (float*)alloc(2097152ull * 4);   // t after attention, f32
  short* tb   = (short*)alloc(2097152ull * 2);   // final t bf16
  short* yb   = (short*)alloc(2097152ull * 2);   // LN2(t) bf16
  short* h1b  = (short*)alloc(8388608ull * 2);   // gelu hidden
  short* qb   = (short*)alloc(16777216ull * 2);  // qn; later tM
  short* utb  = (short*)alloc(16777216ull * 2);  // u^T [B,H,D,L]
  short* Eb   = (short*)alloc(33554432ull * 2);  // E, then P in place
  float* pvp  = (float*)alloc(4194304ull * 4);   // 2 partial sa planes f32
  short* Wstk = (short*)alloc(4194304ull * 2);   // [NhT(4096); U(4096)] x 512
  short* Mstk = (short*)alloc(2097152ull * 2);   // MhT [4096,512]
  short* wop  = (short*)alloc(2097152ull * 2);
  short* w1b  = (short*)alloc(1048576ull * 2);
  short* w2b  = (short*)alloc(1048576ull * 2);
  short* QT   = (short*)alloc(4194304ull * 2);   // [wqT(8); cwqT(8)] heads
  short* KT   = (short*)alloc(4194304ull * 2);   // [wkT(8); cwkT(8)] heads
  short* WVT  = (short*)alloc(2097152ull * 2);   // wv^T per head

  // 1. prep
  prep<<<24576, 256, 0, stream>>>(tokens, ln1g, ln1b, w1, w2, wo,
                                  wq, wk, cwq, cwk, wv,
                                  xb, tokb, w1b, w2b, wop, QT, KT, WVT);
  // 2. builds: NhT (z<8), MhT (z 8..15), U_h (z 16..23)
  gemm_nt<8, 128><<<dim3(4, 4, 24), 256, 0, stream>>>(KT, QT, 512,
      nullptr, nullptr, nullptr, Wstk, Mstk, wop, WVT);
  // 3. qn + u: x * [NhT; U]^T
  gemm256<0><<<dim3(32, 16, 1), 512, 0, stream>>>(xb, Wstk, 512, 0, 0,
      nullptr, qb, utb, nullptr, nullptr);
  // 4. self E
  gemm256<1><<<dim3(10, 1, 32), 512, 0, stream>>>(qb, xb, 512, 524288, 524288,
      nullptr, Eb, nullptr, nullptr, nullptr);
  // 5. self W -> d_out, P = bf16(W) in place over E
  rownorm<1><<<8192, 256, 0, stream>>>(Eb, out_self, Eb);
  // 6. pv_sa: partial sa planes (h 0-3, 4-7)
  pv_sa<<<dim3(8, 8, 8), 256, 0, stream>>>(Eb, utb, pvp);
  // 7. LN2 fused: t = tokens + p0 + p1 -> tf, yb
  ln2_fuse<<<4096, 256, 0, stream>>>(tokens, pvp, pvp + 2097152,
                                     ln2g, ln2b, tf, yb);
  // 8. ffn1 + gelu
  gemm_nt<4, 128><<<dim3(16, 32, 1), 256, 0, stream>>>(yb, w1b, 512,
      b1, nullptr, nullptr, h1b, nullptr, nullptr, nullptr);
  // 9. ffn2 + residuals -> out_t, tb
  gemm_nt<5, 64><<<dim3(8, 32, 1), 256, 0, stream>>>(h1b, w2b, 2048,
      b2, tf, out_t, tb, nullptr, nullptr, nullptr);
  // 10. tM = t * MhT
  gemm256<6><<<dim3(16, 16, 1), 512, 0, stream>>>(tb, Mstk, 512, 0, 0,
      nullptr, qb, nullptr, tb, Mstk);
  // 11. cross E
  gemm256<7><<<dim3(4, 4, 32), 512, 0, stream>>>(qb, tokb, 512, 524288, 524288,
      nullptr, Eb, nullptr, nullptr, nullptr);
  // 12. cross W = E/sum -> d_out
  rownorm<0><<<8192, 256, 0, stream>>>(Eb, out_cross, nullptr);
}

// Round 11
// 463.259 us; speedup vs baseline: 1.5640x; 1.0305x over previous
//
#include <hip/hip_runtime.h>
#include <hip/hip_bf16.h>

// ---------------------------------------------------------------------------
// TransformerDecoderLayer on MI355X. bf16 MFMA, f32 accumulate.
// R11: all GEMMs on the 128x128-tile 2-barrier engine (16 KiB LDS, 2-3
// blocks/CU) — retires the 1-block/CU 256x256 kernel whose prologue/epilogue
// tails had no co-resident block to hide them. Causal granularity 128.
// 12 dispatches.
// ---------------------------------------------------------------------------

typedef __attribute__((ext_vector_type(4))) float f32x4;
typedef __attribute__((ext_vector_type(8))) short bf16x8;

#define SCALE 0.04419417382415922f   // 1/sqrt(512)

__device__ __forceinline__ short f2bf(float f) {
  __hip_bfloat16 h = __float2bfloat16(f);
  short s; __builtin_memcpy(&s, &h, 2); return s;
}
__device__ __forceinline__ float bf2f(short s) {
  unsigned int u = ((unsigned int)(unsigned short)s) << 16;
  float f; __builtin_memcpy(&f, &u, 4); return f;
}

__device__ __forceinline__ void gload16(const void* g, void* lds) {
  __builtin_amdgcn_global_load_lds(
      (const __attribute__((address_space(1))) unsigned int*)g,
      (__attribute__((address_space(3))) unsigned int*)lds, 16, 0, 0);
}

// ---------------- block reductions ----------------
__device__ __forceinline__ float block_sum(float v, float* sm) {
  #pragma unroll
  for (int o = 1; o < 64; o <<= 1) v += __shfl_xor(v, o, 64);
  int w = threadIdx.x >> 6;
  if ((threadIdx.x & 63) == 0) sm[w] = v;
  __syncthreads();
  float r = sm[0] + sm[1] + sm[2] + sm[3];
  __syncthreads();
  return r;
}

// ---------------- prep: LN1+tokb | cvt w1/w2 | permute_wo | 5 transposes ----
__global__ __launch_bounds__(256) void prep(
    const float* __restrict__ tokens, const float* __restrict__ ln1g,
    const float* __restrict__ ln1b,
    const float* __restrict__ w1, const float* __restrict__ w2,
    const float* __restrict__ wo,
    const float* __restrict__ wq, const float* __restrict__ wk,
    const float* __restrict__ cwq, const float* __restrict__ cwk,
    const float* __restrict__ wv,
    short* __restrict__ xb, short* __restrict__ tokb,
    short* __restrict__ w1b, short* __restrict__ w2b,
    short* __restrict__ wop, short* __restrict__ QT, short* __restrict__ KT,
    short* __restrict__ WVT) {
  __shared__ float sm[4];
  __shared__ float tile[32][33];
  const int bid = blockIdx.x;
  if (bid < 4096) {
    size_t row = bid;
    const float2 v = reinterpret_cast<const float2*>(tokens + row * 512)[threadIdx.x];
    short2 ro; ro.x = f2bf(v.x); ro.y = f2bf(v.y);
    reinterpret_cast<short2*>(tokb + row * 512)[threadIdx.x] = ro;
    float mu = block_sum(v.x + v.y, sm) * (1.0f / 512.0f);
    float dx = v.x - mu, dy = v.y - mu;
    float var = block_sum(dx * dx + dy * dy, sm) * (1.0f / 512.0f);
    float rs = rsqrtf(var + 1e-6f);
    int c = threadIdx.x * 2;
    short2 o;
    o.x = f2bf(dx * rs * ln1g[c] + ln1b[c]);
    o.y = f2bf(dy * rs * ln1g[c + 1] + ln1b[c + 1]);
    reinterpret_cast<short2*>(xb + row * 512)[threadIdx.x] = o;
  } else if (bid < 6144) {
    int i = (bid - 4096) * 256 + threadIdx.x;
    const float* src; short* dst; int k;
    if (i < 262144) { src = w1; dst = w1b; k = i; }
    else            { src = w2; dst = w2b; k = i - 262144; }
    float4 v = reinterpret_cast<const float4*>(src)[k];
    short4 o; o.x = f2bf(v.x); o.y = f2bf(v.y); o.z = f2bf(v.z); o.w = f2bf(v.w);
    reinterpret_cast<short4*>(dst)[k] = o;
  } else if (bid < 14336) {
    int i = (bid - 6144) * 256 + threadIdx.x;
    int o = i >> 12, j = i & 4095;
    int h = j >> 9, d = j & 511;
    int h2 = d >> 6, e = d & 63;
    wop[i] = f2bf(wo[(o << 12) + h2 * 512 + h * 64 + e]);
  } else {
    const int idx = bid - 14336;                // 10240: 40 tensor-heads x 256
    const int z = idx >> 8, t = z >> 3, h = z & 7;
    const int tl = idx & 255, by = tl >> 4, bx = tl & 15;
    const float* in = (t == 0) ? wq : (t == 1) ? wk : (t == 2) ? cwq
                    : (t == 3) ? cwk : wv;
    short* out = (t == 0) ? QT : (t == 1) ? KT
               : (t == 2) ? (QT + 2097152) : (t == 3) ? (KT + 2097152) : WVT;
    const int tx = threadIdx.x & 31, ty = threadIdx.x >> 5;
    const size_t base = (size_t)h * 262144;
    #pragma unroll
    for (int r = 0; r < 4; ++r) {
      const int o = by * 32 + ty + r * 8;
      tile[ty + r * 8][tx] = in[base + (size_t)o * 512 + bx * 32 + tx];
    }
    __syncthreads();
    #pragma unroll
    for (int r = 0; r < 4; ++r) {
      const int d = bx * 32 + ty + r * 8;
      out[base + (size_t)d * 512 + by * 32 + tx] = f2bf(tile[tx][ty + r * 8]);
    }
  }
}

// ---------------- LN2 fused: t = tokens + p0 + p1 -> tf (f32) + yb (bf16) --
__global__ __launch_bounds__(256) void ln2_fuse(
    const float* __restrict__ tokens,
    const float* __restrict__ p0, const float* __restrict__ p1,
    const float* __restrict__ gw, const float* __restrict__ bw,
    float* __restrict__ tf, short* __restrict__ yb) {
  __shared__ float sm[4];
  size_t row = blockIdx.x;
  const size_t i2 = row * 256 + threadIdx.x;
  const float2 tv = reinterpret_cast<const float2*>(tokens)[i2];
  const float2 a2 = reinterpret_cast<const float2*>(p0)[i2];
  const float2 b2 = reinterpret_cast<const float2*>(p1)[i2];
  float x0 = tv.x + a2.x + b2.x, x1 = tv.y + a2.y + b2.y;
  float2 o2; o2.x = x0; o2.y = x1;
  reinterpret_cast<float2*>(tf)[i2] = o2;
  float mu = block_sum(x0 + x1, sm) * (1.0f / 512.0f);
  float dx = x0 - mu, dy = x1 - mu;
  float var = block_sum(dx * dx + dy * dy, sm) * (1.0f / 512.0f);
  float rs = rsqrtf(var + 1e-6f);
  int c = threadIdx.x * 2;
  short2 o;
  o.x = f2bf(dx * rs * gw[c] + bw[c]);
  o.y = f2bf(dy * rs * gw[c + 1] + bw[c + 1]);
  reinterpret_cast<short2*>(yb + row * 512)[threadIdx.x] = o;
}

// ---------------- rownorm: W = E/rowsum -> d_out; CAUSAL also P=bf16(W) ----
// Causal granularity 128 (tile size of the logits GEMM).
template<int CAUSAL>
__global__ __launch_bounds__(256) void rownorm(const short* __restrict__ E,
    float* __restrict__ W, short* __restrict__ pout) {
  const int wv = threadIdx.x >> 6, l = threadIdx.x & 63;
  const size_t row = (size_t)blockIdx.x * 4 + wv;
  const int r = (int)(row & 1023);
  const int live_end = CAUSAL ? (((r >> 7) + 1) << 7) : 1024;
  const short* ep = E + row * 1024;
  float s = 0.f;
  #pragma unroll
  for (int c = 0; c < 2; ++c) {
    const int c0 = c * 512 + l * 8;
    if (c0 < live_end) {
      bf16x8 v = *reinterpret_cast<const bf16x8*>(ep + c0);
      #pragma unroll
      for (int j = 0; j < 8; ++j) s += bf2f(v[j]);
    }
  }
  #pragma unroll
  for (int o = 1; o < 64; o <<= 1) s += __shfl_xor(s, o, 64);
  const float inv = 1.0f / s;
  float* wp = W + row * 1024;
  #pragma unroll
  for (int c = 0; c < 4; ++c) {
    const int c0 = c * 256 + l * 4;
    float4 o4;
    if (c0 < live_end) {
      short4 v = *reinterpret_cast<const short4*>(ep + c0);
      o4.x = bf2f(v.x) * inv; o4.y = bf2f(v.y) * inv;
      o4.z = bf2f(v.z) * inv; o4.w = bf2f(v.w) * inv;
      if (CAUSAL)
        *reinterpret_cast<short4*>(pout + row * 1024 + c0) =
            make_short4(f2bf(o4.x), f2bf(o4.y), f2bf(o4.z), f2bf(o4.w));
    } else { o4.x = o4.y = o4.z = o4.w = 0.f; }
    *reinterpret_cast<float4*>(wp + c0) = o4;
  }
}

// ===========================================================================
// 128xBN-tile 2-barrier GEMM (16 KiB LDS at BN=128 -> 2-3 blocks/CU).
// EPI 0: x*[NhT;U] -> qn [B,H,L,D] (bout), u^T [B,H,D,L] (bout2); grid 64x32
// EPI 1: self E=exp(.*SCALE-8) bf16; triangular 128-tiles, z=(b,h); A stride
//        524288, B (=xb) per-batch stride; diagonal tile masked to exact 0
// EPI 4: ffn1-gelu   EPI 5: ffn2 (+residuals)   EPI 6: tM = t*MhT
// EPI 7: cross E bf16; z=(b,h), B (=tokb) per-batch
// EPI 8: builds: z<16 NhT/MhT = NT(KT,QT); z>=16 U_h = NT(wop_h[lda4096],WVT)
// ===========================================================================
template<int EPI, int BN>
__global__ __launch_bounds__(256, 2) void gemm_nt(
    const short* __restrict__ A, const short* __restrict__ Bw,
    int K, const float* __restrict__ fin, const float* __restrict__ fin2,
    float* __restrict__ fout, short* __restrict__ bout,
    short* __restrict__ bout2,
    const short* __restrict__ A3, const short* __restrict__ B3) {
  constexpr int NJ = BN / 32;
  __shared__ short As[128 * 32];
  __shared__ short Bs[BN * 32];
  const int tid = threadIdx.x;
  const int w = tid >> 6, l = tid & 63;
  const int wr = w >> 1, wc = w & 1;
  const int lr = l & 15, kh = l >> 4;
  int bx = blockIdx.x, by = blockIdx.y;
  const int z = blockIdx.z;
  if constexpr (EPI == 1) {                 // triangular 128-tiles: bx<=by
    int idx = blockIdx.x;
    by = (int)((sqrtf(8.0f * idx + 1.0f) - 1.0f) * 0.5f);
    while ((by + 1) * (by + 2) / 2 <= idx) ++by;
    while (by * (by + 1) / 2 > idx) --by;
    bx = idx - by * (by + 1) / 2;
  }
  const int bm = by * 128, bn = bx * BN;
  const int ar = w * 16 + (l >> 2);
  const int ac = (l & 3) * 8;
  const short* Ab = A; const short* Bb = Bw;
  int lda = K;
  if constexpr (EPI == 1 || EPI == 7) {
    Ab = A + (size_t)z * 524288;            // per-(b,h)
    Bb = Bw + (size_t)(z >> 3) * 524288;    // per-batch
  } else if constexpr (EPI == 8) {
    const int zz = blockIdx.z;
    if (zz < 16) { Ab = A + (size_t)zz * 262144; Bb = Bw + (size_t)zz * 262144; }
    else { Ab = A3 + (size_t)(zz - 16) * 512; Bb = B3 + (size_t)(zz - 16) * 262144;
           lda = 4096; }
  }

  f32x4 acc[4][NJ];
  #pragma unroll
  for (int i = 0; i < 4; ++i)
    #pragma unroll
    for (int j = 0; j < NJ; ++j) acc[i][j] = (f32x4){0.f, 0.f, 0.f, 0.f};

  for (int k0 = 0; k0 < K; k0 += 32) {
    #pragma unroll
    for (int c = 0; c < 2; ++c)
      gload16(Ab + (size_t)(bm + c * 64 + ar) * lda + k0 + ac, &As[c * 2048 + w * 512]);
    #pragma unroll
    for (int c = 0; c < BN / 64; ++c)
      gload16(Bb + (size_t)(bn + c * 64 + ar) * K + k0 + ac, &Bs[c * 2048 + w * 512]);
    __syncthreads();
    bf16x8 af[4], bfr[NJ];
    #pragma unroll
    for (int i = 0; i < 4; ++i)
      af[i] = *reinterpret_cast<const bf16x8*>(&As[(wr * 64 + i * 16 + lr) * 32 + kh * 8]);
    #pragma unroll
    for (int j = 0; j < NJ; ++j)
      bfr[j] = *reinterpret_cast<const bf16x8*>(&Bs[(wc * (BN / 2) + j * 16 + lr) * 32 + kh * 8]);
    #pragma unroll
    for (int i = 0; i < 4; ++i)
      #pragma unroll
      for (int j = 0; j < NJ; ++j)
        acc[i][j] = __builtin_amdgcn_mfma_f32_16x16x32_bf16(bfr[j], af[i], acc[i][j], 0, 0, 0);
    __syncthreads();
  }

  // Swapped-operand C layout: lane owns 1 row (lr field) x 4 consecutive cols.
  #pragma unroll
  for (int i = 0; i < 4; ++i) {
    const int grow = bm + wr * 64 + i * 16 + lr;
    #pragma unroll
    for (int j = 0; j < NJ; ++j) {
      const int gcol0 = bn + wc * (BN / 2) + j * 16 + kh * 4;
      const float v0 = acc[i][j][0], v1 = acc[i][j][1];
      const float v2 = acc[i][j][2], v3 = acc[i][j][3];
      if constexpr (EPI == 0) {
        const int b = grow >> 10, lw = grow & 1023;
        if (bn < 4096) {    // qn [B,H,L,D]
          const int h = gcol0 >> 9, o = gcol0 & 511;
          *reinterpret_cast<short4*>(&bout[(((size_t)(b * 8 + h)) * 1024 + lw) * 512 + o]) =
              make_short4(f2bf(v0), f2bf(v1), f2bf(v2), f2bf(v3));
        } else {            // u^T [B,H,D,L]
          const int n2 = gcol0 - 4096, h = n2 >> 9, o = n2 & 511;
          const size_t base = ((size_t)(b * 8 + h)) * 512;
          bout2[(base + o + 0) * 1024 + lw] = f2bf(v0);
          bout2[(base + o + 1) * 1024 + lw] = f2bf(v1);
          bout2[(base + o + 2) * 1024 + lw] = f2bf(v2);
          bout2[(base + o + 3) * 1024 + lw] = f2bf(v3);
        }
      } else if constexpr (EPI == 1) {
        short4 o;
        o.x = (gcol0 + 0 > grow) ? (short)0 : f2bf(__expf(v0 * SCALE - 8.0f));
        o.y = (gcol0 + 1 > grow) ? (short)0 : f2bf(__expf(v1 * SCALE - 8.0f));
        o.z = (gcol0 + 2 > grow) ? (short)0 : f2bf(__expf(v2 * SCALE - 8.0f));
        o.w = (gcol0 + 3 > grow) ? (short)0 : f2bf(__expf(v3 * SCALE - 8.0f));
        *reinterpret_cast<short4*>(&bout[(size_t)z * 1048576 + (size_t)grow * 1024 + gcol0]) = o;
      } else if constexpr (EPI == 4) {
        const float4 b4 = *reinterpret_cast<const float4*>(&fin[gcol0]);
        const float x0 = v0 + b4.x, x1 = v1 + b4.y, x2 = v2 + b4.z, x3 = v3 + b4.w;
        const float g0 = 0.5f * x0 * (1.0f + erff(x0 * 0.70710678118654752f));
        const float g1 = 0.5f * x1 * (1.0f + erff(x1 * 0.70710678118654752f));
        const float g2 = 0.5f * x2 * (1.0f + erff(x2 * 0.70710678118654752f));
        const float g3 = 0.5f * x3 * (1.0f + erff(x3 * 0.70710678118654752f));
        *reinterpret_cast<short4*>(&bout[(size_t)grow * 2048 + gcol0]) =
            make_short4(f2bf(g0), f2bf(g1), f2bf(g2), f2bf(g3));
      } else if constexpr (EPI == 5) {
        const size_t idx = (size_t)grow * 512 + gcol0;
        const float4 a4 = *reinterpret_cast<const float4*>(&fin2[idx]);
        const float4 b4 = *reinterpret_cast<const float4*>(&fin[gcol0]);
        float4 f;
        f.x = a4.x + v0 + b4.x; f.y = a4.y + v1 + b4.y;
        f.z = a4.z + v2 + b4.z; f.w = a4.w + v3 + b4.w;
        *reinterpret_cast<float4*>(&fout[idx]) = f;
        *reinterpret_cast<short4*>(&bout[idx]) =
            make_short4(f2bf(f.x), f2bf(f.y), f2bf(f.z), f2bf(f.w));
      } else if constexpr (EPI == 6) {
        const int b = grow >> 10, lw = grow & 1023;
        const int h = gcol0 >> 9, o = gcol0 & 511;
        *reinterpret_cast<short4*>(&bout[(((size_t)(b * 8 + h)) * 1024 + lw) * 512 + o]) =
            make_short4(f2bf(v0), f2bf(v1), f2bf(v2), f2bf(v3));
      } else if constexpr (EPI == 7) {
        short4 o;
        o.x = f2bf(__expf(v0 * SCALE - 8.0f));
        o.y = f2bf(__expf(v1 * SCALE - 8.0f));
        o.z = f2bf(__expf(v2 * SCALE - 8.0f));
        o.w = f2bf(__expf(v3 * SCALE - 8.0f));
        *reinterpret_cast<short4*>(&bout[(size_t)z * 1048576 + (size_t)grow * 1024 + gcol0]) = o;
      } else if constexpr (EPI == 8) {
        const int zz = blockIdx.z;
        short* outp = (zz < 8)  ? (bout + (size_t)zz * 262144)
                    : (zz < 16) ? (bout2 + (size_t)(zz - 8) * 262144)
                                : (bout + 2097152 + (size_t)(zz - 16) * 262144);
        *reinterpret_cast<short4*>(&outp[(size_t)grow * 512 + gcol0]) =
            make_short4(f2bf(v0), f2bf(v1), f2bf(v2), f2bf(v3));
      }
    }
  }
}

// ---------------- pv_sa: part[half] = sum_{h in half} P_bh * uT_bh^T -------
// 128x64 tiles; K-loop over 4 heads x causal-truncated k. Grid (8,8,8).
__global__ __launch_bounds__(256, 2) void pv_sa(
    const short* __restrict__ P, const short* __restrict__ uT,
    float* __restrict__ part) {
  __shared__ short As[128 * 32];
  __shared__ short Bs[64 * 32];
  const int tid = threadIdx.x;
  const int w = tid >> 6, l = tid & 63;
  const int wr = w >> 1, wc = w & 1;
  const int lr = l & 15, kh = l >> 4;
  const int bn = blockIdx.x * 64;
  const int bm = blockIdx.y * 128;          // within batch
  const int b = blockIdx.z >> 1, half = blockIdx.z & 1;
  const int ar = w * 16 + (l >> 2);
  const int ac = (l & 3) * 8;
  const int kend = bm + 128;                // causal: P cols > row are 0

  f32x4 acc[4][2];
  #pragma unroll
  for (int i = 0; i < 4; ++i)
    #pragma unroll
    for (int j = 0; j < 2; ++j) acc[i][j] = (f32x4){0.f, 0.f, 0.f, 0.f};

  for (int h = half * 4; h < half * 4 + 4; ++h) {
    const short* Ab = P + ((size_t)(b * 8 + h) << 20);
    const short* Bb = uT + (size_t)(b * 8 + h) * 524288;
    for (int k0 = 0; k0 < kend; k0 += 32) {
      #pragma unroll
      for (int c = 0; c < 2; ++c)
        gload16(Ab + (size_t)(bm + c * 64 + ar) * 1024 + k0 + ac, &As[c * 2048 + w * 512]);
      gload16(Bb + (size_t)(bn + ar) * 1024 + k0 + ac, &Bs[w * 512]);
      __syncthreads();
      bf16x8 af[4], bfr[2];
      #pragma unroll
      for (int i = 0; i < 4; ++i)
        af[i] = *reinterpret_cast<const bf16x8*>(&As[(wr * 64 + i * 16 + lr) * 32 + kh * 8]);
      #pragma unroll
      for (int j = 0; j < 2; ++j)
        bfr[j] = *reinterpret_cast<const bf16x8*>(&Bs[(wc * 32 + j * 16 + lr) * 32 + kh * 8]);
      #pragma unroll
      for (int i = 0; i < 4; ++i)
        #pragma unroll
        for (int j = 0; j < 2; ++j)
          acc[i][j] = __builtin_amdgcn_mfma_f32_16x16x32_bf16(bfr[j], af[i], acc[i][j], 0, 0, 0);
      __syncthreads();
    }
  }

  float* plane = part + (size_t)half * 2097152;
  #pragma unroll
  for (int i = 0; i < 4; ++i) {
    const int grow = bm + wr * 64 + i * 16 + lr;
    #pragma unroll
    for (int j = 0; j < 2; ++j) {
      const int gcol0 = bn + wc * 32 + j * 16 + kh * 4;
      float4 f;
      f.x = acc[i][j][0]; f.y = acc[i][j][1];
      f.z = acc[i][j][2]; f.w = acc[i][j][3];
      *reinterpret_cast<float4*>(&plane[((size_t)(b * 1024 + grow)) * 512 + gcol0]) = f;
    }
  }
}

// ---------------------------------------------------------------------------
extern "C" void kernel_launch(void* const* d_in, const int* in_sizes, int n_in,
                              void* d_out, int out_size, void* d_ws, size_t ws_size,
                              hipStream_t stream) {
  const float* tokens = (const float*)d_in[0];
  const float* ln1g = (const float*)d_in[3];
  const float* ln1b = (const float*)d_in[4];
  const float* ln2g = (const float*)d_in[5];
  const float* ln2b = (const float*)d_in[6];
  const float* wq = (const float*)d_in[7];
  const float* wk = (const float*)d_in[8];
  const float* wv = (const float*)d_in[9];
  const float* wo = (const float*)d_in[10];
  const float* w1 = (const float*)d_in[11];
  const float* b1 = (const float*)d_in[12];
  const float* w2 = (const float*)d_in[13];
  const float* b2 = (const float*)d_in[14];
  const float* cwk = (const float*)d_in[15];
  const float* cwq = (const float*)d_in[17];

  float* out_t = (float*)d_out;
  float* out_self = out_t + 2097152;
  float* out_cross = out_self + 33554432;

  char* ws = (char*)d_ws;
  size_t off = 0;
  auto alloc = [&](size_t bytes) -> void* {
    void* p = ws + off; off = (off + bytes + 255) & ~(size_t)255; return p;
  };
  short* xb   = (short*)alloc(2097152ull * 2);   // LN1(tokens) bf16
  short* tokb = (short*)alloc(2097152ull * 2);   // tokens bf16
  float* tf   = (float*)alloc(2097152ull * 4);   // t after attention, f32
  short* tb   = (short*)alloc(2097152ull * 2);   // final t bf16
  short* yb   = (short*)alloc(2097152ull * 2);   // LN2(t) bf16
  short* h1b  = (short*)alloc(8388608ull * 2);   // gelu hidden
  short* qb   = (short*)alloc(16777216ull * 2);  // qn; later tM
  short* utb  = (short*)alloc(16777216ull * 2);  // u^T [B,H,D,L]
  short* Eb   = (short*)alloc(33554432ull * 2);  // E, then P in place
  float* pvp  = (float*)alloc(4194304ull * 4);   // 2 partial sa planes f32
  short* Wstk = (short*)alloc(4194304ull * 2);   // [NhT(4096); U(4096)] x 512
  short* Mstk = (short*)alloc(2097152ull * 2);   // MhT [4096,512]
  short* wop  = (short*)alloc(2097152ull * 2);
  short* w1b  = (short*)alloc(1048576ull * 2);
  short* w2b  = (short*)alloc(1048576ull * 2);
  short* QT   = (short*)alloc(4194304ull * 2);   // [wqT(8); cwqT(8)] heads
  short* KT   = (short*)alloc(4194304ull * 2);   // [wkT(8); cwkT(8)] heads
  short* WVT  = (short*)alloc(2097152ull * 2);   // wv^T per head

  // 1. prep
  prep<<<24576, 256, 0, stream>>>(tokens, ln1g, ln1b, w1, w2, wo,
                                  wq, wk, cwq, cwk, wv,
                                  xb, tokb, w1b, w2b, wop, QT, KT, WVT);
  // 2. builds: NhT (z<8), MhT (z 8..15), U_h (z 16..23)
  gemm_nt<8, 128><<<dim3(4, 4, 24), 256, 0, stream>>>(KT, QT, 512,
      nullptr, nullptr, nullptr, Wstk, Mstk, wop, WVT);
  // 3. qn + u: x * [NhT; U]^T   (2048 blocks)
  gemm_nt<0, 128><<<dim3(64, 32, 1), 256, 0, stream>>>(xb, Wstk, 512,
      nullptr, nullptr, nullptr, qb, utb, nullptr, nullptr);
  // 4. self E: triangular 128-tiles (36) x 32 heads  (1152 blocks)
  gemm_nt<1, 128><<<dim3(36, 1, 32), 256, 0, stream>>>(qb, xb, 512,
      nullptr, nullptr, nullptr, Eb, nullptr, nullptr, nullptr);
  // 5. self W -> d_out, P = bf16(W) in place over E
  rownorm<1><<<8192, 256, 0, stream>>>(Eb, out_self, Eb);
  // 6. pv_sa: partial sa planes (h 0-3, 4-7)
  pv_sa<<<dim3(8, 8, 8), 256, 0, stream>>>(Eb, utb, pvp);
  // 7. LN2 fused: t = tokens + p0 + p1 -> tf, yb
  ln2_fuse<<<4096, 256, 0, stream>>>(tokens, pvp, pvp + 2097152,
                                     ln2g, ln2b, tf, yb);
  // 8. ffn1 + gelu
  gemm_nt<4, 128><<<dim3(16, 32, 1), 256, 0, stream>>>(yb, w1b, 512,
      b1, nullptr, nullptr, h1b, nullptr, nullptr, nullptr);
  // 9. ffn2 + residuals -> out_t, tb
  gemm_nt<5, 64><<<dim3(8, 32, 1), 256, 0, stream>>>(h1b, w2b, 2048,
      b2, tf, out_t, tb, nullptr, nullptr, nullptr);
  // 10. tM = t * MhT   (1024 blocks)
  gemm_nt<6, 128><<<dim3(32, 32, 1), 256, 0, stream>>>(tb, Mstk, 512,
      nullptr, nullptr, nullptr, qb, nullptr, tb, Mstk);
  // 11. cross E   (2048 blocks)
  gemm_nt<7, 128><<<dim3(8, 8, 32), 256, 0, stream>>>(qb, tokb, 512,
      nullptr, nullptr, nullptr, Eb, nullptr, nullptr, nullptr);
  // 12. cross W = E/sum -> d_out
  rownorm<0><<<8192, 256, 0, stream>>>(Eb, out_cross, nullptr);
}

// Round 12
// 420.800 us; speedup vs baseline: 1.7218x; 1.1009x over previous
//
#include <hip/hip_runtime.h>
#include <hip/hip_bf16.h>

// ---------------------------------------------------------------------------
// TransformerDecoderLayer on MI355X. bf16 MFMA, f32 accumulate.
// R12: 128-tile engine widened to BK=64 (half the barriers) + m201-style
// chunk-XOR LDS swizzle (kills the 8-way ds_read bank conflict carried since
// R1; source pre-swizzled, dest linear, read swizzled — rule #21).
// 12 dispatches, structure otherwise identical to R11.
// ---------------------------------------------------------------------------

typedef __attribute__((ext_vector_type(4))) float f32x4;
typedef __attribute__((ext_vector_type(8))) short bf16x8;

#define SCALE 0.04419417382415922f   // 1/sqrt(512)

__device__ __forceinline__ short f2bf(float f) {
  __hip_bfloat16 h = __float2bfloat16(f);
  short s; __builtin_memcpy(&s, &h, 2); return s;
}
__device__ __forceinline__ float bf2f(short s) {
  unsigned int u = ((unsigned int)(unsigned short)s) << 16;
  float f; __builtin_memcpy(&f, &u, 4); return f;
}

__device__ __forceinline__ void gload16(const void* g, void* lds) {
  __builtin_amdgcn_global_load_lds(
      (const __attribute__((address_space(1))) unsigned int*)g,
      (__attribute__((address_space(3))) unsigned int*)lds, 16, 0, 0);
}

// ---------------- block reductions ----------------
__device__ __forceinline__ float block_sum(float v, float* sm) {
  #pragma unroll
  for (int o = 1; o < 64; o <<= 1) v += __shfl_xor(v, o, 64);
  int w = threadIdx.x >> 6;
  if ((threadIdx.x & 63) == 0) sm[w] = v;
  __syncthreads();
  float r = sm[0] + sm[1] + sm[2] + sm[3];
  __syncthreads();
  return r;
}

// ---------------- prep: LN1+tokb | cvt w1/w2 | permute_wo | 5 transposes ----
__global__ __launch_bounds__(256) void prep(
    const float* __restrict__ tokens, const float* __restrict__ ln1g,
    const float* __restrict__ ln1b,
    const float* __restrict__ w1, const float* __restrict__ w2,
    const float* __restrict__ wo,
    const float* __restrict__ wq, const float* __restrict__ wk,
    const float* __restrict__ cwq, const float* __restrict__ cwk,
    const float* __restrict__ wv,
    short* __restrict__ xb, short* __restrict__ tokb,
    short* __restrict__ w1b, short* __restrict__ w2b,
    short* __restrict__ wop, short* __restrict__ QT, short* __restrict__ KT,
    short* __restrict__ WVT) {
  __shared__ float sm[4];
  __shared__ float tile[32][33];
  const int bid = blockIdx.x;
  if (bid < 4096) {
    size_t row = bid;
    const float2 v = reinterpret_cast<const float2*>(tokens + row * 512)[threadIdx.x];
    short2 ro; ro.x = f2bf(v.x); ro.y = f2bf(v.y);
    reinterpret_cast<short2*>(tokb + row * 512)[threadIdx.x] = ro;
    float mu = block_sum(v.x + v.y, sm) * (1.0f / 512.0f);
    float dx = v.x - mu, dy = v.y - mu;
    float var = block_sum(dx * dx + dy * dy, sm) * (1.0f / 512.0f);
    float rs = rsqrtf(var + 1e-6f);
    int c = threadIdx.x * 2;
    short2 o;
    o.x = f2bf(dx * rs * ln1g[c] + ln1b[c]);
    o.y = f2bf(dy * rs * ln1g[c + 1] + ln1b[c + 1]);
    reinterpret_cast<short2*>(xb + row * 512)[threadIdx.x] = o;
  } else if (bid < 6144) {
    int i = (bid - 4096) * 256 + threadIdx.x;
    const float* src; short* dst; int k;
    if (i < 262144) { src = w1; dst = w1b; k = i; }
    else            { src = w2; dst = w2b; k = i - 262144; }
    float4 v = reinterpret_cast<const float4*>(src)[k];
    short4 o; o.x = f2bf(v.x); o.y = f2bf(v.y); o.z = f2bf(v.z); o.w = f2bf(v.w);
    reinterpret_cast<short4*>(dst)[k] = o;
  } else if (bid < 14336) {
    int i = (bid - 6144) * 256 + threadIdx.x;
    int o = i >> 12, j = i & 4095;
    int h = j >> 9, d = j & 511;
    int h2 = d >> 6, e = d & 63;
    wop[i] = f2bf(wo[(o << 12) + h2 * 512 + h * 64 + e]);
  } else {
    const int idx = bid - 14336;                // 10240: 40 tensor-heads x 256
    const int z = idx >> 8, t = z >> 3, h = z & 7;
    const int tl = idx & 255, by = tl >> 4, bx = tl & 15;
    const float* in = (t == 0) ? wq : (t == 1) ? wk : (t == 2) ? cwq
                    : (t == 3) ? cwk : wv;
    short* out = (t == 0) ? QT : (t == 1) ? KT
               : (t == 2) ? (QT + 2097152) : (t == 3) ? (KT + 2097152) : WVT;
    const int tx = threadIdx.x & 31, ty = threadIdx.x >> 5;
    const size_t base = (size_t)h * 262144;
    #pragma unroll
    for (int r = 0; r < 4; ++r) {
      const int o = by * 32 + ty + r * 8;
      tile[ty + r * 8][tx] = in[base + (size_t)o * 512 + bx * 32 + tx];
    }
    __syncthreads();
    #pragma unroll
    for (int r = 0; r < 4; ++r) {
      const int d = bx * 32 + ty + r * 8;
      out[base + (size_t)d * 512 + by * 32 + tx] = f2bf(tile[tx][ty + r * 8]);
    }
  }
}

// ---------------- LN2 fused: t = tokens + p0 + p1 -> tf (f32) + yb (bf16) --
__global__ __launch_bounds__(256) void ln2_fuse(
    const float* __restrict__ tokens,
    const float* __restrict__ p0, const float* __restrict__ p1,
    const float* __restrict__ gw, const float* __restrict__ bw,
    float* __restrict__ tf, short* __restrict__ yb) {
  __shared__ float sm[4];
  size_t row = blockIdx.x;
  const size_t i2 = row * 256 + threadIdx.x;
  const float2 tv = reinterpret_cast<const float2*>(tokens)[i2];
  const float2 a2 = reinterpret_cast<const float2*>(p0)[i2];
  const float2 b2 = reinterpret_cast<const float2*>(p1)[i2];
  float x0 = tv.x + a2.x + b2.x, x1 = tv.y + a2.y + b2.y;
  float2 o2; o2.x = x0; o2.y = x1;
  reinterpret_cast<float2*>(tf)[i2] = o2;
  float mu = block_sum(x0 + x1, sm) * (1.0f / 512.0f);
  float dx = x0 - mu, dy = x1 - mu;
  float var = block_sum(dx * dx + dy * dy, sm) * (1.0f / 512.0f);
  float rs = rsqrtf(var + 1e-6f);
  int c = threadIdx.x * 2;
  short2 o;
  o.x = f2bf(dx * rs * gw[c] + bw[c]);
  o.y = f2bf(dy * rs * gw[c + 1] + bw[c + 1]);
  reinterpret_cast<short2*>(yb + row * 512)[threadIdx.x] = o;
}

// ---------------- rownorm: W = E/rowsum -> d_out; CAUSAL also P=bf16(W) ----
template<int CAUSAL>
__global__ __launch_bounds__(256) void rownorm(const short* __restrict__ E,
    float* __restrict__ W, short* __restrict__ pout) {
  const int wv = threadIdx.x >> 6, l = threadIdx.x & 63;
  const size_t row = (size_t)blockIdx.x * 4 + wv;
  const int r = (int)(row & 1023);
  const int live_end = CAUSAL ? (((r >> 7) + 1) << 7) : 1024;
  const short* ep = E + row * 1024;
  float s = 0.f;
  #pragma unroll
  for (int c = 0; c < 2; ++c) {
    const int c0 = c * 512 + l * 8;
    if (c0 < live_end) {
      bf16x8 v = *reinterpret_cast<const bf16x8*>(ep + c0);
      #pragma unroll
      for (int j = 0; j < 8; ++j) s += bf2f(v[j]);
    }
  }
  #pragma unroll
  for (int o = 1; o < 64; o <<= 1) s += __shfl_xor(s, o, 64);
  const float inv = 1.0f / s;
  float* wp = W + row * 1024;
  #pragma unroll
  for (int c = 0; c < 4; ++c) {
    const int c0 = c * 256 + l * 4;
    float4 o4;
    if (c0 < live_end) {
      short4 v = *reinterpret_cast<const short4*>(ep + c0);
      o4.x = bf2f(v.x) * inv; o4.y = bf2f(v.y) * inv;
      o4.z = bf2f(v.z) * inv; o4.w = bf2f(v.w) * inv;
      if (CAUSAL)
        *reinterpret_cast<short4*>(pout + row * 1024 + c0) =
            make_short4(f2bf(o4.x), f2bf(o4.y), f2bf(o4.z), f2bf(o4.w));
    } else { o4.x = o4.y = o4.z = o4.w = 0.f; }
    *reinterpret_cast<float4*>(wp + c0) = o4;
  }
}

// ===========================================================================
// 128xBN-tile 2-barrier GEMM, BK=64, chunk-XOR swizzled LDS.
// LDS[R][phys] = glob[R][phys ^ (R&7)] (8-short chunks); dest linear for
// gload_lds (lane l writes 16B at l*16 within each 32-row chunk).
// Read: logical chunk c = ks*4+kh at phys c ^ (lr&7) -> 2 lanes/bank (free).
// EPI 0: x*[NhT;U] -> qn, u^T    EPI 1: self E (triangular, z=(b,h))
// EPI 4: ffn1-gelu   EPI 5: ffn2   EPI 6: tM   EPI 7: cross E
// EPI 8: builds (z<16: NhT/MhT; z>=16: U_h, A strided lda=4096)
// ===========================================================================
template<int EPI, int BN>
__global__ __launch_bounds__(256, 2) void gemm_nt(
    const short* __restrict__ A, const short* __restrict__ Bw,
    int K, const float* __restrict__ fin, const float* __restrict__ fin2,
    float* __restrict__ fout, short* __restrict__ bout,
    short* __restrict__ bout2,
    const short* __restrict__ A3, const short* __restrict__ B3) {
  constexpr int NJ = BN / 32;
  __shared__ short As[128 * 64];
  __shared__ short Bs[BN * 64];
  const int tid = threadIdx.x;
  const int w = tid >> 6, l = tid & 63;
  const int wr = w >> 1, wc = w & 1;
  const int lr = l & 15, kh = l >> 4;
  const int sx = lr & 7;
  int bx = blockIdx.x, by = blockIdx.y;
  const int z = blockIdx.z;
  if constexpr (EPI == 1) {                 // triangular 128-tiles: bx<=by
    int idx = blockIdx.x;
    by = (int)((sqrtf(8.0f * idx + 1.0f) - 1.0f) * 0.5f);
    while ((by + 1) * (by + 2) / 2 <= idx) ++by;
    while (by * (by + 1) / 2 > idx) --by;
    bx = idx - by * (by + 1) / 2;
  }
  const int bm = by * 128, bn = bx * BN;
  const int ar = w * 8 + (l >> 3);          // row within 32-row stage chunk
  const int ac = ((l & 7) ^ (ar & 7)) << 3; // pre-swizzled global col (shorts)
  const short* Ab = A; const short* Bb = Bw;
  int lda = K;
  if constexpr (EPI == 1 || EPI == 7) {
    Ab = A + (size_t)z * 524288;            // per-(b,h)
    Bb = Bw + (size_t)(z >> 3) * 524288;    // per-batch
  } else if constexpr (EPI == 8) {
    const int zz = blockIdx.z;
    if (zz < 16) { Ab = A + (size_t)zz * 262144; Bb = Bw + (size_t)zz * 262144; }
    else { Ab = A3 + (size_t)(zz - 16) * 512; Bb = B3 + (size_t)(zz - 16) * 262144;
           lda = 4096; }
  }

  f32x4 acc[4][NJ];
  #pragma unroll
  for (int i = 0; i < 4; ++i)
    #pragma unroll
    for (int j = 0; j < NJ; ++j) acc[i][j] = (f32x4){0.f, 0.f, 0.f, 0.f};

  for (int k0 = 0; k0 < K; k0 += 64) {
    #pragma unroll
    for (int c = 0; c < 4; ++c)
      gload16(Ab + (size_t)(bm + c * 32 + ar) * lda + k0 + ac, &As[c * 2048 + w * 512]);
    #pragma unroll
    for (int c = 0; c < BN / 32; ++c)
      gload16(Bb + (size_t)(bn + c * 32 + ar) * K + k0 + ac, &Bs[c * 2048 + w * 512]);
    __syncthreads();
    bf16x8 af[4][2], bfr[NJ][2];
    #pragma unroll
    for (int i = 0; i < 4; ++i) {
      const int row_ = wr * 64 + i * 16 + lr;
      #pragma unroll
      for (int ks = 0; ks < 2; ++ks)
        af[i][ks] = *reinterpret_cast<const bf16x8*>(
            &As[row_ * 64 + ((((ks << 2) + kh) ^ sx) << 3)]);
    }
    #pragma unroll
    for (int j = 0; j < NJ; ++j) {
      const int row_ = wc * (BN / 2) + j * 16 + lr;
      #pragma unroll
      for (int ks = 0; ks < 2; ++ks)
        bfr[j][ks] = *reinterpret_cast<const bf16x8*>(
            &Bs[row_ * 64 + ((((ks << 2) + kh) ^ sx) << 3)]);
    }
    #pragma unroll
    for (int i = 0; i < 4; ++i)
      #pragma unroll
      for (int j = 0; j < NJ; ++j)
        #pragma unroll
        for (int ks = 0; ks < 2; ++ks)
          acc[i][j] = __builtin_amdgcn_mfma_f32_16x16x32_bf16(
              bfr[j][ks], af[i][ks], acc[i][j], 0, 0, 0);
    __syncthreads();
  }

  // Swapped-operand C layout: lane owns 1 row (lr field) x 4 consecutive cols.
  #pragma unroll
  for (int i = 0; i < 4; ++i) {
    const int grow = bm + wr * 64 + i * 16 + lr;
    #pragma unroll
    for (int j = 0; j < NJ; ++j) {
      const int gcol0 = bn + wc * (BN / 2) + j * 16 + kh * 4;
      const float v0 = acc[i][j][0], v1 = acc[i][j][1];
      const float v2 = acc[i][j][2], v3 = acc[i][j][3];
      if constexpr (EPI == 0) {
        const int b = grow >> 10, lw = grow & 1023;
        if (bn < 4096) {    // qn [B,H,L,D]
          const int h = gcol0 >> 9, o = gcol0 & 511;
          *reinterpret_cast<short4*>(&bout[(((size_t)(b * 8 + h)) * 1024 + lw) * 512 + o]) =
              make_short4(f2bf(v0), f2bf(v1), f2bf(v2), f2bf(v3));
        } else {            // u^T [B,H,D,L]
          const int n2 = gcol0 - 4096, h = n2 >> 9, o = n2 & 511;
          const size_t base = ((size_t)(b * 8 + h)) * 512;
          bout2[(base + o + 0) * 1024 + lw] = f2bf(v0);
          bout2[(base + o + 1) * 1024 + lw] = f2bf(v1);
          bout2[(base + o + 2) * 1024 + lw] = f2bf(v2);
          bout2[(base + o + 3) * 1024 + lw] = f2bf(v3);
        }
      } else if constexpr (EPI == 1) {
        short4 o;
        o.x = (gcol0 + 0 > grow) ? (short)0 : f2bf(__expf(v0 * SCALE - 8.0f));
        o.y = (gcol0 + 1 > grow) ? (short)0 : f2bf(__expf(v1 * SCALE - 8.0f));
        o.z = (gcol0 + 2 > grow) ? (short)0 : f2bf(__expf(v2 * SCALE - 8.0f));
        o.w = (gcol0 + 3 > grow) ? (short)0 : f2bf(__expf(v3 * SCALE - 8.0f));
        *reinterpret_cast<short4*>(&bout[(size_t)z * 1048576 + (size_t)grow * 1024 + gcol0]) = o;
      } else if constexpr (EPI == 4) {
        const float4 b4 = *reinterpret_cast<const float4*>(&fin[gcol0]);
        const float x0 = v0 + b4.x, x1 = v1 + b4.y, x2 = v2 + b4.z, x3 = v3 + b4.w;
        const float g0 = 0.5f * x0 * (1.0f + erff(x0 * 0.70710678118654752f));
        const float g1 = 0.5f * x1 * (1.0f + erff(x1 * 0.70710678118654752f));
        const float g2 = 0.5f * x2 * (1.0f + erff(x2 * 0.70710678118654752f));
        const float g3 = 0.5f * x3 * (1.0f + erff(x3 * 0.70710678118654752f));
        *reinterpret_cast<short4*>(&bout[(size_t)grow * 2048 + gcol0]) =
            make_short4(f2bf(g0), f2bf(g1), f2bf(g2), f2bf(g3));
      } else if constexpr (EPI == 5) {
        const size_t idx = (size_t)grow * 512 + gcol0;
        const float4 a4 = *reinterpret_cast<const float4*>(&fin2[idx]);
        const float4 b4 = *reinterpret_cast<const float4*>(&fin[gcol0]);
        float4 f;
        f.x = a4.x + v0 + b4.x; f.y = a4.y + v1 + b4.y;
        f.z = a4.z + v2 + b4.z; f.w = a4.w + v3 + b4.w;
        *reinterpret_cast<float4*>(&fout[idx]) = f;
        *reinterpret_cast<short4*>(&bout[idx]) =
            make_short4(f2bf(f.x), f2bf(f.y), f2bf(f.z), f2bf(f.w));
      } else if constexpr (EPI == 6) {
        const int b = grow >> 10, lw = grow & 1023;
        const int h = gcol0 >> 9, o = gcol0 & 511;
        *reinterpret_cast<short4*>(&bout[(((size_t)(b * 8 + h)) * 1024 + lw) * 512 + o]) =
            make_short4(f2bf(v0), f2bf(v1), f2bf(v2), f2bf(v3));
      } else if constexpr (EPI == 7) {
        short4 o;
        o.x = f2bf(__expf(v0 * SCALE - 8.0f));
        o.y = f2bf(__expf(v1 * SCALE - 8.0f));
        o.z = f2bf(__expf(v2 * SCALE - 8.0f));
        o.w = f2bf(__expf(v3 * SCALE - 8.0f));
        *reinterpret_cast<short4*>(&bout[(size_t)z * 1048576 + (size_t)grow * 1024 + gcol0]) = o;
      } else if constexpr (EPI == 8) {
        const int zz = blockIdx.z;
        short* outp = (zz < 8)  ? (bout + (size_t)zz * 262144)
                    : (zz < 16) ? (bout2 + (size_t)(zz - 8) * 262144)
                                : (bout + 2097152 + (size_t)(zz - 16) * 262144);
        *reinterpret_cast<short4*>(&outp[(size_t)grow * 512 + gcol0]) =
            make_short4(f2bf(v0), f2bf(v1), f2bf(v2), f2bf(v3));
      }
    }
  }
}

// ---------------- pv_sa: part[half] = sum_{h in half} P_bh * uT_bh^T -------
// 128x64 tiles, BK=64 swizzled; K-loop over 4 heads x causal-truncated k.
__global__ __launch_bounds__(256, 2) void pv_sa(
    const short* __restrict__ P, const short* __restrict__ uT,
    float* __restrict__ part) {
  __shared__ short As[128 * 64];
  __shared__ short Bs[64 * 64];
  const int tid = threadIdx.x;
  const int w = tid >> 6, l = tid & 63;
  const int wr = w >> 1, wc = w & 1;
  const int lr = l & 15, kh = l >> 4;
  const int sx = lr & 7;
  const int bn = blockIdx.x * 64;
  const int bm = blockIdx.y * 128;          // within batch
  const int b = blockIdx.z >> 1, half = blockIdx.z & 1;
  const int ar = w * 8 + (l >> 3);
  const int ac = ((l & 7) ^ (ar & 7)) << 3;
  const int kend = bm + 128;                // causal: P cols > row are 0

  f32x4 acc[4][2];
  #pragma unroll
  for (int i = 0; i < 4; ++i)
    #pragma unroll
    for (int j = 0; j < 2; ++j) acc[i][j] = (f32x4){0.f, 0.f, 0.f, 0.f};

  for (int h = half * 4; h < half * 4 + 4; ++h) {
    const short* Ab = P + ((size_t)(b * 8 + h) << 20);
    const short* Bb = uT + (size_t)(b * 8 + h) * 524288;
    for (int k0 = 0; k0 < kend; k0 += 64) {
      #pragma unroll
      for (int c = 0; c < 4; ++c)
        gload16(Ab + (size_t)(bm + c * 32 + ar) * 1024 + k0 + ac, &As[c * 2048 + w * 512]);
      #pragma unroll
      for (int c = 0; c < 2; ++c)
        gload16(Bb + (size_t)(bn + c * 32 + ar) * 1024 + k0 + ac, &Bs[c * 2048 + w * 512]);
      __syncthreads();
      bf16x8 af[4][2], bfr[2][2];
      #pragma unroll
      for (int i = 0; i < 4; ++i) {
        const int row_ = wr * 64 + i * 16 + lr;
        #pragma unroll
        for (int ks = 0; ks < 2; ++ks)
          af[i][ks] = *reinterpret_cast<const bf16x8*>(
              &As[row_ * 64 + ((((ks << 2) + kh) ^ sx) << 3)]);
      }
      #pragma unroll
      for (int j = 0; j < 2; ++j) {
        const int row_ = wc * 32 + j * 16 + lr;
        #pragma unroll
        for (int ks = 0; ks < 2; ++ks)
          bfr[j][ks] = *reinterpret_cast<const bf16x8*>(
              &Bs[row_ * 64 + ((((ks << 2) + kh) ^ sx) << 3)]);
      }
      #pragma unroll
      for (int i = 0; i < 4; ++i)
        #pragma unroll
        for (int j = 0; j < 2; ++j)
          #pragma unroll
          for (int ks = 0; ks < 2; ++ks)
            acc[i][j] = __builtin_amdgcn_mfma_f32_16x16x32_bf16(
                bfr[j][ks], af[i][ks], acc[i][j], 0, 0, 0);
      __syncthreads();
    }
  }

  float* plane = part + (size_t)half * 2097152;
  #pragma unroll
  for (int i = 0; i < 4; ++i) {
    const int grow = bm + wr * 64 + i * 16 + lr;
    #pragma unroll
    for (int j = 0; j < 2; ++j) {
      const int gcol0 = bn + wc * 32 + j * 16 + kh * 4;
      float4 f;
      f.x = acc[i][j][0]; f.y = acc[i][j][1];
      f.z = acc[i][j][2]; f.w = acc[i][j][3];
      *reinterpret_cast<float4*>(&plane[((size_t)(b * 1024 + grow)) * 512 + gcol0]) = f;
    }
  }
}

// ---------------------------------------------------------------------------
extern "C" void kernel_launch(void* const* d_in, const int* in_sizes, int n_in,
                              void* d_out, int out_size, void* d_ws, size_t ws_size,
                              hipStream_t stream) {
  const float* tokens = (const float*)d_in[0];
  const float* ln1g = (const float*)d_in[3];
  const float* ln1b = (const float*)d_in[4];
  const float* ln2g = (const float*)d_in[5];
  const float* ln2b = (const float*)d_in[6];
  const float* wq = (const float*)d_in[7];
  const float* wk = (const float*)d_in[8];
  const float* wv = (const float*)d_in[9];
  const float* wo = (const float*)d_in[10];
  const float* w1 = (const float*)d_in[11];
  const float* b1 = (const float*)d_in[12];
  const float* w2 = (const float*)d_in[13];
  const float* b2 = (const float*)d_in[14];
  const float* cwk = (const float*)d_in[15];
  const float* cwq = (const float*)d_in[17];

  float* out_t = (float*)d_out;
  float* out_self = out_t + 2097152;
  float* out_cross = out_self + 33554432;

  char* ws = (char*)d_ws;
  size_t off = 0;
  auto alloc = [&](size_t bytes) -> void* {
    void* p = ws + off; off = (off + bytes + 255) & ~(size_t)255; return p;
  };
  short* xb   = (short*)alloc(2097152ull * 2);   // LN1(tokens) bf16
  short* tokb = (short*)alloc(2097152ull * 2);   // tokens bf16
  float* tf   = (float*)alloc(2097152ull * 4);   // t after attention, f32
  short* tb   = (short*)alloc(2097152ull * 2);   // final t bf16
  short* yb   = (short*)alloc(2097152ull * 2);   // LN2(t) bf16
  short* h1b  = (short*)alloc(8388608ull * 2);   // gelu hidden
  short* qb   = (short*)alloc(16777216ull * 2);  // qn; later tM
  short* utb  = (short*)alloc(16777216ull * 2);  // u^T [B,H,D,L]
  short* Eb   = (short*)alloc(33554432ull * 2);  // E, then P in place
  float* pvp  = (float*)alloc(4194304ull * 4);   // 2 partial sa planes f32
  short* Wstk = (short*)alloc(4194304ull * 2);   // [NhT(4096); U(4096)] x 512
  short* Mstk = (short*)alloc(2097152ull * 2);   // MhT [4096,512]
  short* wop  = (short*)alloc(2097152ull * 2);
  short* w1b  = (short*)alloc(1048576ull * 2);
  short* w2b  = (short*)alloc(1048576ull * 2);
  short* QT   = (short*)alloc(4194304ull * 2);   // [wqT(8); cwqT(8)] heads
  short* KT   = (short*)alloc(4194304ull * 2);   // [wkT(8); cwkT(8)] heads
  short* WVT  = (short*)alloc(2097152ull * 2);   // wv^T per head

  // 1. prep
  prep<<<24576, 256, 0, stream>>>(tokens, ln1g, ln1b, w1, w2, wo,
                                  wq, wk, cwq, cwk, wv,
                                  xb, tokb, w1b, w2b, wop, QT, KT, WVT);
  // 2. builds: NhT (z<8), MhT (z 8..15), U_h (z 16..23)
  gemm_nt<8, 128><<<dim3(4, 4, 24), 256, 0, stream>>>(KT, QT, 512,
      nullptr, nullptr, nullptr, Wstk, Mstk, wop, WVT);
  // 3. qn + u: x * [NhT; U]^T   (2048 blocks)
  gemm_nt<0, 128><<<dim3(64, 32, 1), 256, 0, stream>>>(xb, Wstk, 512,
      nullptr, nullptr, nullptr, qb, utb, nullptr, nullptr);
  // 4. self E: triangular 128-tiles (36) x 32 heads  (1152 blocks)
  gemm_nt<1, 128><<<dim3(36, 1, 32), 256, 0, stream>>>(qb, xb, 512,
      nullptr, nullptr, nullptr, Eb, nullptr, nullptr, nullptr);
  // 5. self W -> d_out, P = bf16(W) in place over E
  rownorm<1><<<8192, 256, 0, stream>>>(Eb, out_self, Eb);
  // 6. pv_sa: partial sa planes (h 0-3, 4-7)
  pv_sa<<<dim3(8, 8, 8), 256, 0, stream>>>(Eb, utb, pvp);
  // 7. LN2 fused: t = tokens + p0 + p1 -> tf, yb
  ln2_fuse<<<4096, 256, 0, stream>>>(tokens, pvp, pvp + 2097152,
                                     ln2g, ln2b, tf, yb);
  // 8. ffn1 + gelu
  gemm_nt<4, 128><<<dim3(16, 32, 1), 256, 0, stream>>>(yb, w1b, 512,
      b1, nullptr, nullptr, h1b, nullptr, nullptr, nullptr);
  // 9. ffn2 + residuals -> out_t, tb
  gemm_nt<5, 64><<<dim3(8, 32, 1), 256, 0, stream>>>(h1b, w2b, 2048,
      b2, tf, out_t, tb, nullptr, nullptr, nullptr);
  // 10. tM = t * MhT   (1024 blocks)
  gemm_nt<6, 128><<<dim3(32, 32, 1), 256, 0, stream>>>(tb, Mstk, 512,
      nullptr, nullptr, nullptr, qb, nullptr, tb, Mstk);
  // 11. cross E   (2048 blocks)
  gemm_nt<7, 128><<<dim3(8, 8, 32), 256, 0, stream>>>(qb, tokb, 512,
      nullptr, nullptr, nullptr, Eb, nullptr, nullptr, nullptr);
  // 12. cross W = E/sum -> d_out
  rownorm<0><<<8192, 256, 0, stream>>>(Eb, out_cross, nullptr);
}